// Round 5
// baseline (555.446 us; speedup 1.0000x reference)
//
#include <hip/hip_runtime.h>

typedef unsigned short u16;
typedef unsigned int u32;

#define NNODES 20000
#define NEDGES 640000
// GAMMA = 1/(2*(sqrt(2)/15)^2) = 56.25 exactly
#define RBF_GAMMA 56.25f
#define SQRT2 1.4142135623730951f
#define PITCH 132    // fp32 LDS row pitch
#define BPITCH 136   // bf16 LDS row pitch (u16)

typedef __bf16 bf16x8 __attribute__((ext_vector_type(8)));
typedef __bf16 bf16x2 __attribute__((ext_vector_type(2)));
typedef float f32x4 __attribute__((ext_vector_type(4)));

__device__ __forceinline__ float b2f(u16 u) {
    union { float f; u32 i; } x; x.i = ((u32)u) << 16; return x.f;
}
__device__ __forceinline__ float hi2f(u32 w) {
    union { float f; u32 i; } x; x.i = w & 0xffff0000u; return x.f;
}
__device__ __forceinline__ float lo2f(u32 w) {
    union { float f; u32 i; } x; x.i = w << 16; return x.f;
}
__device__ __forceinline__ u16 f2b(float f) {
    union { float f; u32 i; } x; x.f = f;
    u32 r = (x.i + 0x7fffu + ((x.i >> 16) & 1u)) >> 16;
    return (u16)r;
}
// pack 2 fp32 -> 2 bf16 (RNE)
__device__ __forceinline__ u32 pack2(float a, float b) {
#if __has_builtin(__builtin_amdgcn_cvt_pk_bf16_f32)
    union { bf16x2 v; u32 u; } x;
    x.v = __builtin_amdgcn_cvt_pk_bf16_f32(a, b);
    return x.u;
#else
    return (u32)f2b(a) | ((u32)f2b(b) << 16);
#endif
}
__device__ __forceinline__ float silu(float v) {
    return v * __builtin_amdgcn_rcpf(1.0f + __expf(-v));
}
__device__ __forceinline__ void fma4(float4 w, float4 s, float& acc) {
    acc = fmaf(w.x, s.x, acc);
    acc = fmaf(w.y, s.y, acc);
    acc = fmaf(w.z, s.z, acc);
    acc = fmaf(w.w, s.w, acc);
}

// ---------------- sort by dst (counting sort) ----------------
__global__ __launch_bounds__(256) void k_hist(const int* __restrict__ ei, int* __restrict__ hist) {
    int e = blockIdx.x * 256 + threadIdx.x;
    atomicAdd(&hist[ei[NEDGES + e]], 1);
}

__global__ __launch_bounds__(1024) void k_scan(const int* __restrict__ hist,
                                               int* __restrict__ row_ptr,
                                               int* __restrict__ cursor) {
    __shared__ int psum[1024];
    int t = threadIdx.x;
    int base = t * 20;
    int s = 0;
    if (base < NNODES)
        for (int i = 0; i < 20; ++i) s += hist[base + i];
    psum[t] = s;
    __syncthreads();
    for (int off = 1; off < 1024; off <<= 1) {
        int v = (t >= off) ? psum[t - off] : 0;
        __syncthreads();
        psum[t] += v;
        __syncthreads();
    }
    int excl = psum[t] - s;
    if (base < NNODES) {
        int run = excl;
        for (int i = 0; i < 20; ++i) {
            row_ptr[base + i] = run;
            cursor[base + i] = run;
            run += hist[base + i];
        }
    }
    if (t == 1023) row_ptr[NNODES] = psum[1023];
}

__global__ __launch_bounds__(256) void k_scatter(const int* __restrict__ ei, int* __restrict__ cursor,
                                                 int* __restrict__ ssrc, int* __restrict__ sdst) {
    int e = blockIdx.x * 256 + threadIdx.x;
    int d = ei[NEDGES + e];
    int pos = atomicAdd(&cursor[d], 1);
    ssrc[pos] = ei[e];
    sdst[pos] = d;
}

// ---------------- full edge W1 (src 128 rows + rbf 16 + bias) -> 5-kc bf16 B-frag ----------------
// Wf layout per layer: [kc(5)][nt(8)][lane(64)][8]  (20480 u16)
__global__ __launch_bounds__(256) void k_prep_w5(const float* __restrict__ pmw1,
                                                 const float* __restrict__ pmb1,
                                                 u16* __restrict__ Wf) {
    int id = blockIdx.x * 256 + threadIdx.x;   // 7680 total
    if (id >= 7680) return;
    int l = id / 2560; int r = id - l * 2560;
    int kc = r >> 9;
    int r2 = r & 511;
    int nt = r2 >> 6, lane = r2 & 63;
    int col = nt * 16 + (lane & 15);
    alignas(16) u16 tmp[8];
    #pragma unroll
    for (int jj = 0; jj < 8; ++jj) {
        int kl = (lane >> 4) * 8 + jj;
        float v;
        if (kc < 4) {
            v = pmw1[l * 34816 + (kc * 32 + kl) * 128 + col];     // W1 src rows 0..127
        } else {
            if (kl < 16) v = pmw1[l * 34816 + (256 + kl) * 128 + col];  // rbf rows
            else if (kl == 16) v = pmb1[l * 128 + col];                 // bias
            else v = 0.f;
        }
        tmp[jj] = f2b(v);
    }
    *(uint4*)(Wf + (size_t)id * 8) = *(const uint4*)tmp;
}

// ---------------- generic fp32 [128][128] -> bf16 B-frag layout ----------------
// per-matrix layout: [kc(4)][nt(8)][lane(64)][8]  (16384 u16 each)
// mats: 0..2 Ywdst, 3..5 V2, 6 ow1, 7..9 V1h, 10..12 V1l, 13 nw2h, 14 nw2l
struct BfM { const float* s[15]; };
__global__ __launch_bounds__(256) void k_prep_bf(BfM bf, u16* __restrict__ dst) {
    int id = blockIdx.x * 256 + threadIdx.x;   // 30720 total
    if (id >= 30720) return;
    int mat = id >> 11;
    bool lomode = (mat >= 10 && mat != 13);
    int r = id & 2047;
    int kc = r >> 9;
    int r2 = r & 511;
    int nt = r2 >> 6, lane = r2 & 63;
    int col = nt * 16 + (lane & 15);
    int kb = kc * 32 + (lane >> 4) * 8;
    const float* src = bf.s[mat];
    alignas(16) u16 tmp[8];
    #pragma unroll
    for (int jj = 0; jj < 8; ++jj) {
        float v = src[(kb + jj) * 128 + col];
        u16 h = f2b(v);
        tmp[jj] = lomode ? f2b(v - b2f(h)) : h;
    }
    *(uint4*)(dst + (size_t)id * 8) = *(const uint4*)tmp;
}

// ---------------- Mp (packed fp32 [k>>2][j][k&3]) -> hi/lo bf16 B-frag ----------------
// Mf layout: [l][hi/lo][16384]
__global__ __launch_bounds__(256) void k_prep_mbf(const float* __restrict__ Mp, u16* __restrict__ dst) {
    int id = blockIdx.x * 256 + threadIdx.x;   // 12288 total
    if (id >= 12288) return;
    int mat = id >> 11;          // 0..5
    int l = mat >> 1, lomode = mat & 1;
    int r = id & 2047;
    int kc = r >> 9;
    int r2 = r & 511;
    int nt = r2 >> 6, lane = r2 & 63;
    int col = nt * 16 + (lane & 15);
    int kb = kc * 32 + (lane >> 4) * 8;
    const float* src = Mp + (size_t)l * 16384;
    alignas(16) u16 tmp[8];
    #pragma unroll
    for (int jj = 0; jj < 8; ++jj) {
        int k = kb + jj;
        float v = src[(k >> 2) * 512 + col * 4 + (k & 3)];
        u16 h = f2b(v);
        tmp[jj] = lomode ? f2b(v - b2f(h)) : h;
    }
    *(uint4*)(dst + (size_t)id * 8) = *(const uint4*)tmp;
}

// ---------------- pack fp32 [K][128] -> [K/4][128][4] ----------------
struct PackM { const float* s[3]; float* d[3]; int K[3]; };
__global__ __launch_bounds__(256) void k_pack(PackM pm) {
    int m = blockIdx.y;
    int idx = blockIdx.x * 256 + threadIdx.x;
    if (idx >= pm.K[m] * 128) return;
    int k = idx >> 7, j = idx & 127;
    pm.d[m][(k >> 2) * 512 + j * 4 + (k & 3)] = pm.s[m][idx];
}

// ---------------- prep: M = W2 @ V1b (per layer, packed) and bv = b2 @ V1b ----------------
__global__ __launch_bounds__(256) void k_prep_m(const float* __restrict__ pmw2,
        const float* __restrict__ pmb2, const float* __restrict__ V1p,
        float* __restrict__ Mp, float* __restrict__ bvv) {
    const int l = blockIdx.y, bx = blockIdx.x;
    const float* V1 = V1p + (size_t)l * 32768;
    const int tid = threadIdx.x;
    const int w = tid >> 6, lane = tid & 63;
    const int cg = lane & 15, ng = lane >> 4;
    const int jc0 = w * 32 + cg * 2, jc1 = jc0 + 1;
    __shared__ alignas(16) float W2L[16][PITCH];
    __shared__ float b2L[128];
    if (bx < 8) {
        const float4* src = (const float4*)(pmw2 + (size_t)l * 16384 + bx * 16 * 128);
        for (int q = tid; q < 512; q += 256) {
            int row = q >> 5, part = q & 31;
            *(float4*)&W2L[row][part * 4] = src[q];
        }
        __syncthreads();
        int r0 = ng * 4;
        float acc[4][2];
        #pragma unroll
        for (int n = 0; n < 4; ++n) { acc[n][0] = 0.f; acc[n][1] = 0.f; }
        for (int mm = 0; mm < 32; ++mm) {
            float4 wa = *(const float4*)(V1 + (32 + mm) * 512 + jc0 * 4);
            float4 wb = *(const float4*)(V1 + (32 + mm) * 512 + jc1 * 4);
            #pragma unroll
            for (int n = 0; n < 4; ++n) {
                float4 s4 = *(const float4*)&W2L[r0 + n][mm * 4];
                fma4(wa, s4, acc[n][0]);
                fma4(wb, s4, acc[n][1]);
            }
        }
        #pragma unroll
        for (int n = 0; n < 4; ++n) {
            int kg = bx * 16 + r0 + n;
            Mp[(size_t)l * 16384 + (kg >> 2) * 512 + jc0 * 4 + (kg & 3)] = acc[n][0];
            Mp[(size_t)l * 16384 + (kg >> 2) * 512 + jc1 * 4 + (kg & 3)] = acc[n][1];
        }
    } else {
        if (tid < 128) b2L[tid] = pmb2[l * 128 + tid];
        __syncthreads();
        if (ng == 0) {
            float a0 = 0.f, a1 = 0.f;
            for (int mm = 0; mm < 32; ++mm) {
                float4 wa = *(const float4*)(V1 + (32 + mm) * 512 + jc0 * 4);
                float4 wb = *(const float4*)(V1 + (32 + mm) * 512 + jc1 * 4);
                float4 s4 = *(const float4*)&b2L[mm * 4];
                fma4(wa, s4, a0);
                fma4(wb, s4, a1);
            }
            bvv[l * 128 + jc0] = a0;
            bvv[l * 128 + jc1] = a1;
        }
    }
}

// ---------------- time embedding -> te -> base1 ----------------
__global__ __launch_bounds__(128) void k_time(const int* __restrict__ tptr,
        const float* __restrict__ tw1, const float* __restrict__ tb1,
        const float* __restrict__ tw2, const float* __restrict__ tb2,
        const float* __restrict__ nw1, const float* __restrict__ nb1,
        float* __restrict__ base1) {
    __shared__ float emb[128], hid[128], te[128];
    int j = threadIdx.x;
    int raw = tptr[0];
    float tv;
    if (raw >= 0 && raw < (1 << 24)) tv = (float)raw;
    else tv = __int_as_float(raw);
    float fr = expf(-9.210340371976184f * (float)(j & 63) / 63.0f);
    float a = tv * fr;
    emb[j] = (j < 64) ? sinf(a) : cosf(a);
    __syncthreads();
    float acc = tb1[j];
    for (int k = 0; k < 128; ++k) acc += emb[k] * tw1[k * 128 + j];
    hid[j] = silu(acc);
    __syncthreads();
    acc = tb2[j];
    for (int k = 0; k < 128; ++k) acc += hid[k] * tw2[k * 128 + j];
    te[j] = acc;
    __syncthreads();
    acc = nb1[j];
    for (int k = 0; k < 128; ++k) acc += te[k] * nw1[(3 + k) * 128 + j];
    base1[j] = acc;
}

// ---------------- input node MLP (MFMA hi/lo GEMM2) + MFMA Ydst + hbf out ----------------
__global__ __launch_bounds__(256) void k_h0(const float* __restrict__ x, const float* __restrict__ base1,
        const float* __restrict__ nw1, const u16* __restrict__ nw2h, const u16* __restrict__ nw2l,
        const float* __restrict__ nb2, const u16* __restrict__ Yw,
        float* __restrict__ hf, u16* __restrict__ hbf, u16* __restrict__ Ydst) {
    const int tid = threadIdx.x;
    const int w = tid >> 6, lane = tid & 63;
    const int cg = lane & 15, ng = lane >> 4;
    const int jc0 = w * 32 + cg * 2, jc1 = jc0 + 1;
    const int n0 = ng * 4;
    const int base = blockIdx.x * 16;
    const int lrow = lane & 15, quad = lane >> 4;
    __shared__ alignas(16) float xl[16][4];
    __shared__ alignas(16) u16 hih[16 * BPITCH], hil[16 * BPITCH];
    __shared__ alignas(16) u16 hb16[16 * BPITCH];
    if (tid < 48) { int n = tid / 3, cc = tid - n * 3; xl[n][cc] = x[(size_t)(base + n) * 3 + cc]; }
    __syncthreads();
    {
        float w0a = nw1[jc0], w0b = nw1[jc1];
        float w1a = nw1[128 + jc0], w1b = nw1[128 + jc1];
        float w2a = nw1[256 + jc0], w2b = nw1[256 + jc1];
        float ba = base1[jc0], bb = base1[jc1];
        #pragma unroll
        for (int n = 0; n < 4; ++n) {
            int row = n0 + n;
            float x0 = xl[row][0], x1 = xl[row][1], x2 = xl[row][2];
            float va = silu(ba + x0 * w0a + x1 * w1a + x2 * w2a);
            float vb = silu(bb + x0 * w0b + x1 * w1b + x2 * w2b);
            u32 hw = pack2(va, vb);
            *(u32*)&hih[row * BPITCH + jc0] = hw;
            *(u32*)&hil[row * BPITCH + jc0] = pack2(va - lo2f(hw), vb - hi2f(hw));
        }
    }
    __syncthreads();
    // GEMM2 (MFMA hi/lo): h = hid @ nw2 + nb2 -> hf (fp32) + hb16 (bf16)
    {
        bf16x8 ah[4], al[4];
        #pragma unroll
        for (int kc = 0; kc < 4; ++kc) {
            ah[kc] = *(const bf16x8*)(hih + lrow * BPITCH + kc * 32 + quad * 8);
            al[kc] = *(const bf16x8*)(hil + lrow * BPITCH + kc * 32 + quad * 8);
        }
        #pragma unroll
        for (int t = 0; t < 2; ++t) {
            int nt = w * 2 + t;
            f32x4 a4 = {0.f, 0.f, 0.f, 0.f};
            #pragma unroll
            for (int kc = 0; kc < 4; ++kc) {
                size_t o = (size_t)((kc * 8 + nt) * 512 + lane * 8);
                bf16x8 bh = *(const bf16x8*)(nw2h + o);
                bf16x8 bl = *(const bf16x8*)(nw2l + o);
                a4 = __builtin_amdgcn_mfma_f32_16x16x32_bf16(ah[kc], bh, a4, 0, 0, 0);
                a4 = __builtin_amdgcn_mfma_f32_16x16x32_bf16(al[kc], bh, a4, 0, 0, 0);
                a4 = __builtin_amdgcn_mfma_f32_16x16x32_bf16(ah[kc], bl, a4, 0, 0, 0);
            }
            int colC = nt * 16 + lrow;
            float bC = nb2[colC];
            #pragma unroll
            for (int r = 0; r < 4; ++r) {
                int R = quad * 4 + r;
                float v = a4[r] + bC;
                hf[(size_t)(base + R) * 128 + colC] = v;
                hb16[R * BPITCH + colC] = f2b(v);
            }
        }
    }
    __syncthreads();
    // MFMA Ydst (dst-only; 4 waves x 2 nt = 8 nt) + hbf copy
    {
        bf16x8 a[4];
        #pragma unroll
        for (int kc = 0; kc < 4; ++kc)
            a[kc] = *(const bf16x8*)(hb16 + lrow * BPITCH + kc * 32 + quad * 8);
        #pragma unroll
        for (int t = 0; t < 2; ++t) {
            int nt = w * 2 + t;
            f32x4 a4 = {0.f, 0.f, 0.f, 0.f};
            #pragma unroll
            for (int kc = 0; kc < 4; ++kc) {
                bf16x8 b = *(const bf16x8*)(Yw + (size_t)((kc * 8 + nt) * 512 + lane * 8));
                a4 = __builtin_amdgcn_mfma_f32_16x16x32_bf16(a[kc], b, a4, 0, 0, 0);
            }
            #pragma unroll
            for (int r = 0; r < 4; ++r)
                Ydst[(size_t)(base + quad * 4 + r) * 128 + nt * 16 + lrow] = f2b(a4[r]);
        }
        for (int q = tid; q < 512; q += 256) {
            int row = q >> 5, part = q & 31;
            *(uint2*)&hbf[(size_t)(base + row) * 128 + part * 4] =
                *(const uint2*)&hb16[row * BPITCH + part * 4];
        }
    }
}

// ---------------- edge kernel: fused Ysrc via K=160 MFMA, proven epilogue ----------------
__global__ __launch_bounds__(512, 8) void k_edge(
        const u16* __restrict__ hbf, const u16* __restrict__ Ydst,
        const float* __restrict__ x,
        const int* __restrict__ ssrc, const int* __restrict__ sdst,
        const u16* __restrict__ Wf,
        float* __restrict__ s_glob) {
    __shared__ alignas(16) u16 sst[128 * 72];   // [col][row] bf16, pitch 72
    __shared__ alignas(16) u16 hs[64 * BPITCH]; // staged h_src rows (bf16, pitch 136)
    __shared__ float rv[64];
    __shared__ int s_d[65];
    __shared__ int s_s[64];
    const int tid = threadIdx.x;
    const int e0 = blockIdx.x * 64;
    if (tid < 64) {
        int s = ssrc[e0 + tid], d = sdst[e0 + tid];
        s_s[tid] = s; s_d[tid] = d;
        float ddx = x[s * 3] - x[d * 3];
        float ddy = x[s * 3 + 1] - x[d * 3 + 1];
        rv[tid] = sqrtf(ddx * ddx + ddy * ddy + 1e-8f);
    } else if (tid == 64) {
        s_d[64] = -1;
    }
    __syncthreads();
    #pragma unroll
    for (int i = 0; i < 2; ++i) {
        int cch = tid + i * 512;
        int e = cch >> 4, part = cch & 15;
        *(uint4*)(hs + e * BPITCH + part * 8) = *(const uint4*)(hbf + (size_t)s_s[e] * 128 + part * 8);
    }
    const int w = tid >> 6, lane = tid & 63;
    const int m = w & 3, nh = w >> 2;
    const int lrow = lane & 15, quad = lane >> 4;
    float r = rv[m * 16 + lrow];
    union { bf16x8 v; u16 u[8]; } af;
    #pragma unroll
    for (int j = 0; j < 8; ++j) {
        int kk = quad * 8 + j;
        float v;
        if (kk < 16) {
            float dd = r - SQRT2 * (float)kk / 15.0f;
            v = __expf(-RBF_GAMMA * dd * dd);
        } else v = (kk == 16) ? 1.0f : 0.0f;
        af.u[j] = f2b(v);
    }
    __syncthreads();   // hs staged
    {
        bf16x8 a[4];
        #pragma unroll
        for (int kc = 0; kc < 4; ++kc)
            a[kc] = *(const bf16x8*)(hs + (m * 16 + lrow) * BPITCH + kc * 32 + quad * 8);
        #pragma unroll
        for (int t = 0; t < 4; ++t) {
            int nt = nh * 4 + t;
            f32x4 a4 = {0.f, 0.f, 0.f, 0.f};
            #pragma unroll
            for (int kc = 0; kc < 4; ++kc) {
                bf16x8 b = *(const bf16x8*)(Wf + (size_t)((kc * 8 + nt) * 512 + lane * 8));
                a4 = __builtin_amdgcn_mfma_f32_16x16x32_bf16(a[kc], b, a4, 0, 0, 0);
            }
            {
                bf16x8 b = *(const bf16x8*)(Wf + (size_t)((4 * 8 + nt) * 512 + lane * 8));
                a4 = __builtin_amdgcn_mfma_f32_16x16x32_bf16(af.v, b, a4, 0, 0, 0);
            }
            int col = nt * 16 + lrow;
            u32 lo = pack2(a4[0], a4[1]);
            u32 hi = pack2(a4[2], a4[3]);
            *(uint2*)(sst + col * 72 + m * 16 + quad * 4) = make_uint2(lo, hi);
        }
    }
    __syncthreads();
    {
        const int col = tid & 127, q = tid >> 7;
        const int r0 = q * 16;
        float a = 0.f;
        int cd = s_d[r0];
        float yd = b2f(Ydst[(size_t)cd * 128 + col]);
        #pragma unroll
        for (int h = 0; h < 2; ++h) {
            uint4 c0 = *(const uint4*)(sst + col * 72 + r0 + h * 8);
            float sv8[8];
            sv8[0] = lo2f(c0.x); sv8[1] = hi2f(c0.x);
            sv8[2] = lo2f(c0.y); sv8[3] = hi2f(c0.y);
            sv8[4] = lo2f(c0.z); sv8[5] = hi2f(c0.z);
            sv8[6] = lo2f(c0.w); sv8[7] = hi2f(c0.w);
            #pragma unroll
            for (int i = 0; i < 8; ++i) {
                int rr = r0 + h * 8 + i;
                int nd = s_d[rr + 1];
                float v = sv8[i] + yd;
                a += silu(v);
                bool last = (h == 1 && i == 7);
                if (last || nd != cd) {
                    atomicAdd(&s_glob[(size_t)cd * 128 + col], a);
                    a = 0.f;
                    if (!last && nd != cd)
                        yd = b2f(Ydst[(size_t)nd * 128 + col]);
                }
                cd = nd;
            }
        }
    }
}

// ---------------- node update: GEMM2' via MFMA (hi/lo bf16), GEMM3 via MFMA,
//                  MFMA Ydst + hbf (l<2) or fused output MLP (l==2) ----------------
__global__ __launch_bounds__(256) void k_node(float* __restrict__ s_glob, const int* __restrict__ row_ptr,
        float* __restrict__ hf,
        const u16* __restrict__ V1h, const u16* __restrict__ V1l,
        const u16* __restrict__ Mh, const u16* __restrict__ Ml,
        const u16* __restrict__ V2bf,
        const float* __restrict__ bv, const float* __restrict__ c1, const float* __restrict__ c2,
        const float* __restrict__ lng, const float* __restrict__ lnb,
        const u16* __restrict__ Yw,
        u16* __restrict__ hbf, u16* __restrict__ Ydst,
        const u16* __restrict__ ow1bf, const float* __restrict__ ob1,
        const float* __restrict__ ow2, const float* __restrict__ ob2,
        float* __restrict__ out) {
    const int tid = threadIdx.x;
    const int w = tid >> 6, lane = tid & 63;
    const int cg = lane & 15, ng = lane >> 4;
    const int jc0 = w * 32 + cg * 2, jc1 = jc0 + 1;
    const int n0 = ng * 4;
    const int base = blockIdx.x * 16;
    const int lrow = lane & 15, quad = lane >> 4;
    __shared__ alignas(16) float hv[16][PITCH];
    __shared__ alignas(16) float xs[16][PITCH];
    __shared__ alignas(16) u16 hvh[16 * BPITCH], hvl[16 * BPITCH];
    __shared__ alignas(16) u16 svh[16 * BPITCH], svl[16 * BPITCH];
    __shared__ alignas(16) u16 ybf[16 * BPITCH];
    __shared__ float mv[16][2];
    __shared__ int rp[17];

    if (tid < 17) rp[tid] = row_ptr[base + tid];
    {
        const float4* sg4 = (const float4*)(s_glob + (size_t)base * 128);
        float4* sg4w = (float4*)(s_glob + (size_t)base * 128);
        const float4* hg4 = (const float4*)(hf + (size_t)base * 128);
        for (int q = tid; q < 512; q += 256) {
            int row = q >> 5, part = q & 31;
            float4 s = sg4[q];
            float4 h = hg4[q];
            if (Yw != nullptr) sg4w[q] = make_float4(0.f, 0.f, 0.f, 0.f);
            *(float4*)&hv[row][part * 4] = h;
            u32 hw0 = pack2(h.x, h.y), hw1 = pack2(h.z, h.w);
            *(uint2*)&hvh[row * BPITCH + part * 4] = make_uint2(hw0, hw1);
            u32 hl0 = pack2(h.x - lo2f(hw0), h.y - hi2f(hw0));
            u32 hl1 = pack2(h.z - lo2f(hw1), h.w - hi2f(hw1));
            *(uint2*)&hvl[row * BPITCH + part * 4] = make_uint2(hl0, hl1);
            u32 sw0 = pack2(s.x, s.y), sw1 = pack2(s.z, s.w);
            *(uint2*)&svh[row * BPITCH + part * 4] = make_uint2(sw0, sw1);
            u32 sl0 = pack2(s.x - lo2f(sw0), s.y - hi2f(sw0));
            u32 sl1 = pack2(s.z - lo2f(sw1), s.w - hi2f(sw1));
            *(uint2*)&svl[row * BPITCH + part * 4] = make_uint2(sl0, sl1);
        }
    }
    __syncthreads();

    // ---- GEMM2' (MFMA, hi/lo bf16): u_pre = hv@V1a + sv@M + deg*bv + c1 ; uv = silu -> ybf ----
    {
        bf16x8 ahh[4], ahl[4], ash[4], asl[4];
        #pragma unroll
        for (int kc = 0; kc < 4; ++kc) {
            ahh[kc] = *(const bf16x8*)(hvh + lrow * BPITCH + kc * 32 + quad * 8);
            ahl[kc] = *(const bf16x8*)(hvl + lrow * BPITCH + kc * 32 + quad * 8);
            ash[kc] = *(const bf16x8*)(svh + lrow * BPITCH + kc * 32 + quad * 8);
            asl[kc] = *(const bf16x8*)(svl + lrow * BPITCH + kc * 32 + quad * 8);
        }
        float dg[4];
        #pragma unroll
        for (int r = 0; r < 4; ++r)
            dg[r] = (float)(rp[quad * 4 + r + 1] - rp[quad * 4 + r]);
        #pragma unroll
        for (int t = 0; t < 2; ++t) {
            int nt = w * 2 + t;
            f32x4 a4 = {0.f, 0.f, 0.f, 0.f};
            #pragma unroll
            for (int kc = 0; kc < 4; ++kc) {
                size_t o = (size_t)((kc * 8 + nt) * 512 + lane * 8);
                bf16x8 bh = *(const bf16x8*)(V1h + o);
                bf16x8 bl = *(const bf16x8*)(V1l + o);
                a4 = __builtin_amdgcn_mfma_f32_16x16x32_bf16(ahh[kc], bh, a4, 0, 0, 0);
                a4 = __builtin_amdgcn_mfma_f32_16x16x32_bf16(ahl[kc], bh, a4, 0, 0, 0);
                a4 = __builtin_amdgcn_mfma_f32_16x16x32_bf16(ahh[kc], bl, a4, 0, 0, 0);
                bf16x8 mh = *(const bf16x8*)(Mh + o);
                bf16x8 ml = *(const bf16x8*)(Ml + o);
                a4 = __builtin_amdgcn_mfma_f32_16x16x32_bf16(ash[kc], mh, a4, 0, 0, 0);
                a4 = __builtin_amdgcn_mfma_f32_16x16x32_bf16(asl[kc], mh, a4, 0, 0, 0);
                a4 = __builtin_amdgcn_mfma_f32_16x16x32_bf16(ash[kc], ml, a4, 0, 0, 0);
            }
            int colC = nt * 16 + lrow;
            float bvC = bv[colC], c1C = c1[colC];
            #pragma unroll
            for (int r = 0; r < 4; ++r) {
                float u = a4[r] + dg[r] * bvC + c1C;
                ybf[(quad * 4 + r) * BPITCH + colC] = f2b(silu(u));
            }
        }
    }
    __syncthreads();   // uv(bf16) ready
    // ---- GEMM3 (MFMA): o = uv @ V2 + c2 ; xj = hv + o -> xs (C-layout) ----
    {
        bf16x8 a[4];
        #pragma unroll
        for (int kc = 0; kc < 4; ++kc)
            a[kc] = *(const bf16x8*)(ybf + lrow * BPITCH + kc * 32 + quad * 8);
        #pragma unroll
        for (int t = 0; t < 2; ++t) {
            int nt = w * 2 + t;
            f32x4 a4 = {0.f, 0.f, 0.f, 0.f};
            #pragma unroll
            for (int kc = 0; kc < 4; ++kc) {
                bf16x8 b = *(const bf16x8*)(V2bf + (size_t)((kc * 8 + nt) * 512 + lane * 8));
                a4 = __builtin_amdgcn_mfma_f32_16x16x32_bf16(a[kc], b, a4, 0, 0, 0);
            }
            int colC = nt * 16 + lrow;
            float c2v = c2[colC];
            #pragma unroll
            for (int r = 0; r < 4; ++r) {
                int R = quad * 4 + r;
                xs[R][colC] = a4[r] + c2v + hv[R][colC];
            }
        }
    }
    __syncthreads();
    // ---- LN reduce ----
    {
        int row = tid >> 4, part = tid & 15;
        float4 a = *(const float4*)&xs[row][part * 8];
        float4 b = *(const float4*)&xs[row][part * 8 + 4];
        float s1 = a.x + a.y + a.z + a.w + b.x + b.y + b.z + b.w;
        float s2 = a.x * a.x + a.y * a.y + a.z * a.z + a.w * a.w
                 + b.x * b.x + b.y * b.y + b.z * b.z + b.w * b.w;
        #pragma unroll
        for (int mq = 1; mq < 16; mq <<= 1) {
            s1 += __shfl_xor(s1, mq, 64);
            s2 += __shfl_xor(s2, mq, 64);
        }
        if (part == 0) { mv[row][0] = s1; mv[row][1] = s2; }
    }
    __syncthreads();
    // ---- LN apply (writes y to bf16 tile; hf only when another layer follows) ----
    {
        float ga = lng[jc0], gb = lng[jc1];
        float bba = lnb[jc0], bbb = lnb[jc1];
        #pragma unroll
        for (int n = 0; n < 4; ++n) {
            int row = n0 + n;
            float mu = mv[row][0] * (1.0f / 128.0f);
            float var = mv[row][1] * (1.0f / 128.0f) - mu * mu;
            float rs = rsqrtf(var + 1e-5f);
            float y0 = (xs[row][jc0] - mu) * rs * ga + bba;
            float y1 = (xs[row][jc1] - mu) * rs * gb + bbb;
            if (Yw != nullptr)
                *(float2*)&hf[(size_t)(base + row) * 128 + jc0] = make_float2(y0, y1);
            *(u32*)&ybf[row * BPITCH + jc0] = pack2(y0, y1);
        }
    }
    if (Yw != nullptr) {
        __syncthreads();
        bf16x8 a[4];
        #pragma unroll
        for (int kc = 0; kc < 4; ++kc)
            a[kc] = *(const bf16x8*)(ybf + lrow * BPITCH + kc * 32 + quad * 8);
        #pragma unroll
        for (int t = 0; t < 2; ++t) {
            int nt = w * 2 + t;
            f32x4 a4 = {0.f, 0.f, 0.f, 0.f};
            #pragma unroll
            for (int kc = 0; kc < 4; ++kc) {
                bf16x8 b = *(const bf16x8*)(Yw + (size_t)((kc * 8 + nt) * 512 + lane * 8));
                a4 = __builtin_amdgcn_mfma_f32_16x16x32_bf16(a[kc], b, a4, 0, 0, 0);
            }
            #pragma unroll
            for (int r = 0; r < 4; ++r)
                Ydst[(size_t)(base + quad * 4 + r) * 128 + nt * 16 + lrow] = f2b(a4[r]);
        }
        for (int q = tid; q < 512; q += 256) {
            int row = q >> 5, part = q & 31;
            *(uint2*)&hbf[(size_t)(base + row) * 128 + part * 4] =
                *(const uint2*)&ybf[row * BPITCH + part * 4];
        }
    } else {
        // ---- fused output MLP: hid2 = silu(y @ ow1 + ob1) -> hv ; out = hid2 @ ow2 + ob2 ----
        __syncthreads();
        {
            bf16x8 a[4];
            #pragma unroll
            for (int kc = 0; kc < 4; ++kc)
                a[kc] = *(const bf16x8*)(ybf + lrow * BPITCH + kc * 32 + quad * 8);
            #pragma unroll
            for (int t = 0; t < 2; ++t) {
                int nt = w * 2 + t;
                f32x4 a4 = {0.f, 0.f, 0.f, 0.f};
                #pragma unroll
                for (int kc = 0; kc < 4; ++kc) {
                    bf16x8 b = *(const bf16x8*)(ow1bf + (size_t)((kc * 8 + nt) * 512 + lane * 8));
                    a4 = __builtin_amdgcn_mfma_f32_16x16x32_bf16(a[kc], b, a4, 0, 0, 0);
                }
                int colC = nt * 16 + lrow;
                float b1v = ob1[colC];
                #pragma unroll
                for (int r = 0; r < 4; ++r)
                    hv[quad * 4 + r][colC] = silu(a4[r] + b1v);
            }
        }
        __syncthreads();
        {
            int row = tid >> 4, s = tid & 15;
            float p0 = 0.f, p1 = 0.f, p2 = 0.f;
            #pragma unroll
            for (int kk2 = 0; kk2 < 8; ++kk2) {
                int k = s * 8 + kk2;
                float h2 = hv[row][k];
                p0 = fmaf(h2, ow2[k * 3 + 0], p0);
                p1 = fmaf(h2, ow2[k * 3 + 1], p1);
                p2 = fmaf(h2, ow2[k * 3 + 2], p2);
            }
            #pragma unroll
            for (int mq = 1; mq < 16; mq <<= 1) {
                p0 += __shfl_xor(p0, mq, 64);
                p1 += __shfl_xor(p1, mq, 64);
                p2 += __shfl_xor(p2, mq, 64);
            }
            if (s == 0) {
                float* o = out + (size_t)(base + row) * 3;
                o[0] = p0 + ob2[0];
                o[1] = p1 + ob2[1];
                o[2] = p2 + ob2[2];
            }
        }
    }
}

extern "C" void kernel_launch(void* const* d_in, const int* in_sizes, int n_in,
                              void* d_out, int out_size, void* d_ws, size_t ws_size,
                              hipStream_t stream) {
    const float* x    = (const float*)d_in[0];
    const int* ei     = (const int*)d_in[1];
    const int* tptr   = (const int*)d_in[2];
    const float* tw1  = (const float*)d_in[3];
    const float* tb1  = (const float*)d_in[4];
    const float* tw2  = (const float*)d_in[5];
    const float* tb2  = (const float*)d_in[6];
    const float* nw1  = (const float*)d_in[7];
    const float* nb1  = (const float*)d_in[8];
    const float* nw2  = (const float*)d_in[9];
    const float* nb2  = (const float*)d_in[10];
    const float* pmw1 = (const float*)d_in[11];
    const float* pmb1 = (const float*)d_in[12];
    const float* pmw2 = (const float*)d_in[13];
    const float* pmb2 = (const float*)d_in[14];
    const float* phw1 = (const float*)d_in[15];
    const float* phb1 = (const float*)d_in[16];
    const float* phw2 = (const float*)d_in[17];
    const float* phb2 = (const float*)d_in[18];
    const float* lng  = (const float*)d_in[19];
    const float* lnb  = (const float*)d_in[20];
    const float* ow1  = (const float*)d_in[21];
    const float* ob1  = (const float*)d_in[22];
    const float* ow2  = (const float*)d_in[23];
    const float* ob2  = (const float*)d_in[24];
    float* out = (float*)d_out;

    char* wsp = (char*)d_ws;
    size_t off = 0;
    auto alloc = [&](size_t bytes) -> void* {
        void* p = wsp + off;
        off += (bytes + 255) & ~(size_t)255;
        return p;
    };
    int* hist    = (int*)alloc((size_t)NNODES * 4);
    int* cursor  = (int*)alloc((size_t)NNODES * 4);
    int* row_ptr = (int*)alloc((size_t)(NNODES + 1) * 4);
    int* ssrc    = (int*)alloc((size_t)NEDGES * 4);
    int* sdst    = (int*)alloc((size_t)NEDGES * 4);
    u16* Wf      = (u16*)alloc((size_t)3 * 20480 * 2);    // fused edge W1 (5-kc frags)
    u16* BF      = (u16*)alloc((size_t)15 * 16384 * 2);   // 3 Ywdst + 3 V2 + ow1 + 3 V1h + 3 V1l + nw2h + nw2l
    u16* Mf      = (u16*)alloc((size_t)6 * 16384 * 2);    // per layer M hi/lo frags
    float* base1 = (float*)alloc(128 * 4);
    float* V1p   = (float*)alloc((size_t)3 * 256 * 128 * 4);
    float* Mp    = (float*)alloc((size_t)3 * 128 * 128 * 4);
    float* bvv   = (float*)alloc((size_t)3 * 128 * 4);
    float* hf    = (float*)alloc((size_t)NNODES * 128 * 4);
    u16* hbf     = (u16*)alloc((size_t)NNODES * 128 * 2);
    u16* Ydst    = (u16*)alloc((size_t)NNODES * 128 * 2);
    float* s_glob= (float*)alloc((size_t)NNODES * 128 * 4);

    (void)hipMemsetAsync(hist, 0, (size_t)NNODES * 4, stream);
    k_hist<<<NEDGES / 256, 256, 0, stream>>>(ei, hist);
    k_scan<<<1, 1024, 0, stream>>>(hist, row_ptr, cursor);
    k_scatter<<<NEDGES / 256, 256, 0, stream>>>(ei, cursor, ssrc, sdst);
    k_prep_w5<<<30, 256, 0, stream>>>(pmw1, pmb1, Wf);

    BfM bf;
    for (int l = 0; l < 3; ++l) {
        bf.s[l]     = pmw1 + (size_t)l * 34816 + 16384;   // Ywdst (W1 rows 128..255)
        bf.s[3 + l] = phw2 + (size_t)l * 16384;           // V2
        bf.s[7 + l] = phw1 + (size_t)l * 32768;           // V1a hi
        bf.s[10 + l] = phw1 + (size_t)l * 32768;          // V1a lo
    }
    bf.s[6] = ow1;
    bf.s[13] = nw2;                                       // nw2 hi
    bf.s[14] = nw2;                                       // nw2 lo
    k_prep_bf<<<120, 256, 0, stream>>>(bf, BF);

    PackM pm;
    for (int l = 0; l < 3; ++l) {
        pm.s[l] = phw1 + (size_t)l * 32768; pm.d[l] = V1p + (size_t)l * 32768; pm.K[l] = 256;
    }
    k_pack<<<dim3(128, 3), 256, 0, stream>>>(pm);
    k_prep_m<<<dim3(9, 3), 256, 0, stream>>>(pmw2, pmb2, V1p, Mp, bvv);
    k_prep_mbf<<<48, 256, 0, stream>>>(Mp, Mf);

    k_time<<<1, 128, 0, stream>>>(tptr, tw1, tb1, tw2, tb2, nw1, nb1, base1);
    k_h0<<<1250, 256, 0, stream>>>(x, base1, nw1,
            BF + (size_t)13 * 16384, BF + (size_t)14 * 16384, nb2,
            BF /* Ywdst layer 0 */, hf, hbf, Ydst);

    (void)hipMemsetAsync(s_glob, 0, (size_t)NNODES * 128 * 4, stream);
    for (int l = 0; l < 3; ++l) {
        k_edge<<<NEDGES / 64, 512, 0, stream>>>(hbf, Ydst, x, ssrc, sdst,
                Wf + (size_t)l * 20480, s_glob);
        const u16* YwN = (l < 2) ? (BF + (size_t)(l + 1) * 16384) : nullptr;
        k_node<<<1250, 256, 0, stream>>>(s_glob, row_ptr, hf,
                BF + (size_t)(7 + l) * 16384, BF + (size_t)(10 + l) * 16384,
                Mf + (size_t)(l * 2) * 16384, Mf + (size_t)(l * 2 + 1) * 16384,
                BF + (size_t)(3 + l) * 16384,
                bvv + l * 128, phb1 + l * 128, phb2 + l * 128, lng + l * 128, lnb + l * 128,
                YwN, hbf, Ydst,
                BF + (size_t)6 * 16384, ob1, ow2, ob2, out);
    }
}

// Round 6
// 498.664 us; speedup vs baseline: 1.1139x; 1.1139x over previous
//
#include <hip/hip_runtime.h>

typedef unsigned short u16;
typedef unsigned int u32;

#define NNODES 20000
#define NEDGES 640000
// GAMMA = 1/(2*(sqrt(2)/15)^2) = 56.25 exactly
#define RBF_GAMMA 56.25f
#define SQRT2 1.4142135623730951f
#define PITCH 132    // fp32 LDS row pitch
#define BPITCH 136   // bf16 LDS row pitch (u16)

typedef __bf16 bf16x8 __attribute__((ext_vector_type(8)));
typedef __bf16 bf16x2 __attribute__((ext_vector_type(2)));
typedef float f32x4 __attribute__((ext_vector_type(4)));

__device__ __forceinline__ float b2f(u16 u) {
    union { float f; u32 i; } x; x.i = ((u32)u) << 16; return x.f;
}
__device__ __forceinline__ float hi2f(u32 w) {
    union { float f; u32 i; } x; x.i = w & 0xffff0000u; return x.f;
}
__device__ __forceinline__ float lo2f(u32 w) {
    union { float f; u32 i; } x; x.i = w << 16; return x.f;
}
__device__ __forceinline__ u16 f2b(float f) {
    union { float f; u32 i; } x; x.f = f;
    u32 r = (x.i + 0x7fffu + ((x.i >> 16) & 1u)) >> 16;
    return (u16)r;
}
// pack 2 fp32 -> 2 bf16 (RNE)
__device__ __forceinline__ u32 pack2(float a, float b) {
#if __has_builtin(__builtin_amdgcn_cvt_pk_bf16_f32)
    union { bf16x2 v; u32 u; } x;
    x.v = __builtin_amdgcn_cvt_pk_bf16_f32(a, b);
    return x.u;
#else
    return (u32)f2b(a) | ((u32)f2b(b) << 16);
#endif
}
__device__ __forceinline__ float silu(float v) {
    return v * __builtin_amdgcn_rcpf(1.0f + __expf(-v));
}
__device__ __forceinline__ void fma4(float4 w, float4 s, float& acc) {
    acc = fmaf(w.x, s.x, acc);
    acc = fmaf(w.y, s.y, acc);
    acc = fmaf(w.z, s.z, acc);
    acc = fmaf(w.w, s.w, acc);
}

// ---------------- sort by dst (counting sort) ----------------
__global__ __launch_bounds__(256) void k_hist(const int* __restrict__ ei, int* __restrict__ hist) {
    int e = blockIdx.x * 256 + threadIdx.x;
    atomicAdd(&hist[ei[NEDGES + e]], 1);
}

__global__ __launch_bounds__(1024) void k_scan(const int* __restrict__ hist,
                                               int* __restrict__ row_ptr,
                                               int* __restrict__ cursor) {
    __shared__ int psum[1024];
    int t = threadIdx.x;
    int base = t * 20;
    int s = 0;
    if (base < NNODES)
        for (int i = 0; i < 20; ++i) s += hist[base + i];
    psum[t] = s;
    __syncthreads();
    for (int off = 1; off < 1024; off <<= 1) {
        int v = (t >= off) ? psum[t - off] : 0;
        __syncthreads();
        psum[t] += v;
        __syncthreads();
    }
    int excl = psum[t] - s;
    if (base < NNODES) {
        int run = excl;
        for (int i = 0; i < 20; ++i) {
            row_ptr[base + i] = run;
            cursor[base + i] = run;
            run += hist[base + i];
        }
    }
    if (t == 1023) row_ptr[NNODES] = psum[1023];
}

__global__ __launch_bounds__(256) void k_scatter(const int* __restrict__ ei, int* __restrict__ cursor,
                                                 int* __restrict__ ssrc, int* __restrict__ sdst) {
    int e = blockIdx.x * 256 + threadIdx.x;
    int d = ei[NEDGES + e];
    int pos = atomicAdd(&cursor[d], 1);
    ssrc[pos] = ei[e];
    sdst[pos] = d;
}

// ---------------- merged prep: Wr frags + 18 bf16 B-frag mats + V1 pack + time MLP ----------------
// ids [0,1536): rbf-part W1 rows 256..271 + b1 -> Wr
// ids [1536,38400): 18 fp32[128][128] -> bf16 B-frag (hi: 0..12,16; lo: 13..15,17)
// ids [38400,136704): pack phw1 [256][128] -> [64][128][4] (3 layers)
// block 534: time embedding -> te -> base1
struct PrepAll {
    const float* pmw1; const float* pmb1; u16* Wr;
    const float* bfs[18]; u16* BF;
    const float* pks[3]; float* pkd[3];
    const int* tptr;
    const float* tw1; const float* tb1; const float* tw2; const float* tb2;
    const float* nw1; const float* nb1; float* base1;
};
__global__ __launch_bounds__(256) void k_prep_all(PrepAll pa) {
    const int tid = threadIdx.x;
    if (blockIdx.x == 534) {
        __shared__ float emb[128], hid[128], te[128];
        int j = tid;
        if (j < 128) {
            int raw = pa.tptr[0];
            float tv;
            if (raw >= 0 && raw < (1 << 24)) tv = (float)raw;
            else tv = __int_as_float(raw);
            float fr = expf(-9.210340371976184f * (float)(j & 63) / 63.0f);
            float a = tv * fr;
            emb[j] = (j < 64) ? sinf(a) : cosf(a);
        }
        __syncthreads();
        if (j < 128) {
            float acc = pa.tb1[j];
            for (int k = 0; k < 128; ++k) acc += emb[k] * pa.tw1[k * 128 + j];
            hid[j] = silu(acc);
        }
        __syncthreads();
        if (j < 128) {
            float acc = pa.tb2[j];
            for (int k = 0; k < 128; ++k) acc += hid[k] * pa.tw2[k * 128 + j];
            te[j] = acc;
        }
        __syncthreads();
        if (j < 128) {
            float acc = pa.nb1[j];
            for (int k = 0; k < 128; ++k) acc += te[k] * pa.nw1[(3 + k) * 128 + j];
            pa.base1[j] = acc;
        }
        return;
    }
    int id = blockIdx.x * 256 + tid;
    if (id < 1536) {
        int l = id / 512; int r = id - l * 512;
        int nt = r >> 6, lane = r & 63;
        int col = nt * 16 + (lane & 15);
        alignas(16) u16 tmp[8];
        #pragma unroll
        for (int jj = 0; jj < 8; ++jj) {
            int kk = (lane >> 4) * 8 + jj;
            float v = 0.f;
            if (kk < 16) v = pa.pmw1[l * 34816 + (256 + kk) * 128 + col];
            else if (kk == 16) v = pa.pmb1[l * 128 + col];
            tmp[jj] = f2b(v);
        }
        *(uint4*)(pa.Wr + (size_t)id * 8) = *(const uint4*)tmp;
    } else if (id < 38400) {
        int id2 = id - 1536;
        int mat = id2 >> 11;
        bool lomode = (mat >= 13 && mat != 16);
        int r = id2 & 2047;
        int kc = r >> 9;
        int r2 = r & 511;
        int nt = r2 >> 6, lane = r2 & 63;
        int col = nt * 16 + (lane & 15);
        int kb = kc * 32 + (lane >> 4) * 8;
        const float* src = pa.bfs[mat];
        alignas(16) u16 tmp[8];
        #pragma unroll
        for (int jj = 0; jj < 8; ++jj) {
            float v = src[(kb + jj) * 128 + col];
            u16 h = f2b(v);
            tmp[jj] = lomode ? f2b(v - b2f(h)) : h;
        }
        *(uint4*)(pa.BF + (size_t)id2 * 8) = *(const uint4*)tmp;
    } else {
        int id2 = id - 38400;            // < 98304
        int m = id2 >> 15, r = id2 & 32767;
        int k = r >> 7, j2 = r & 127;
        pa.pkd[m][(k >> 2) * 512 + j2 * 4 + (k & 3)] = pa.pks[m][r];
    }
}

// ---------------- Mp (packed fp32 [k>>2][j][k&3]) -> hi/lo bf16 B-frag ----------------
// Mf layout: [l][hi/lo][16384]
__global__ __launch_bounds__(256) void k_prep_mbf(const float* __restrict__ Mp, u16* __restrict__ dst) {
    int id = blockIdx.x * 256 + threadIdx.x;   // 12288 total
    if (id >= 12288) return;
    int mat = id >> 11;          // 0..5
    int l = mat >> 1, lomode = mat & 1;
    int r = id & 2047;
    int kc = r >> 9;
    int r2 = r & 511;
    int nt = r2 >> 6, lane = r2 & 63;
    int col = nt * 16 + (lane & 15);
    int kb = kc * 32 + (lane >> 4) * 8;
    const float* src = Mp + (size_t)l * 16384;
    alignas(16) u16 tmp[8];
    #pragma unroll
    for (int jj = 0; jj < 8; ++jj) {
        int k = kb + jj;
        float v = src[(k >> 2) * 512 + col * 4 + (k & 3)];
        u16 h = f2b(v);
        tmp[jj] = lomode ? f2b(v - b2f(h)) : h;
    }
    *(uint4*)(dst + (size_t)id * 8) = *(const uint4*)tmp;
}

// ---------------- prep: M = W2 @ V1b (per layer, packed) and bv = b2 @ V1b ----------------
__global__ __launch_bounds__(256) void k_prep_m(const float* __restrict__ pmw2,
        const float* __restrict__ pmb2, const float* __restrict__ V1p,
        float* __restrict__ Mp, float* __restrict__ bvv) {
    const int l = blockIdx.y, bx = blockIdx.x;
    const float* V1 = V1p + (size_t)l * 32768;
    const int tid = threadIdx.x;
    const int w = tid >> 6, lane = tid & 63;
    const int cg = lane & 15, ng = lane >> 4;
    const int jc0 = w * 32 + cg * 2, jc1 = jc0 + 1;
    __shared__ alignas(16) float W2L[16][PITCH];
    __shared__ float b2L[128];
    if (bx < 8) {
        const float4* src = (const float4*)(pmw2 + (size_t)l * 16384 + bx * 16 * 128);
        for (int q = tid; q < 512; q += 256) {
            int row = q >> 5, part = q & 31;
            *(float4*)&W2L[row][part * 4] = src[q];
        }
        __syncthreads();
        int r0 = ng * 4;
        float acc[4][2];
        #pragma unroll
        for (int n = 0; n < 4; ++n) { acc[n][0] = 0.f; acc[n][1] = 0.f; }
        for (int mm = 0; mm < 32; ++mm) {
            float4 wa = *(const float4*)(V1 + (32 + mm) * 512 + jc0 * 4);
            float4 wb = *(const float4*)(V1 + (32 + mm) * 512 + jc1 * 4);
            #pragma unroll
            for (int n = 0; n < 4; ++n) {
                float4 s4 = *(const float4*)&W2L[r0 + n][mm * 4];
                fma4(wa, s4, acc[n][0]);
                fma4(wb, s4, acc[n][1]);
            }
        }
        #pragma unroll
        for (int n = 0; n < 4; ++n) {
            int kg = bx * 16 + r0 + n;
            Mp[(size_t)l * 16384 + (kg >> 2) * 512 + jc0 * 4 + (kg & 3)] = acc[n][0];
            Mp[(size_t)l * 16384 + (kg >> 2) * 512 + jc1 * 4 + (kg & 3)] = acc[n][1];
        }
    } else {
        if (tid < 128) b2L[tid] = pmb2[l * 128 + tid];
        __syncthreads();
        if (ng == 0) {
            float a0 = 0.f, a1 = 0.f;
            for (int mm = 0; mm < 32; ++mm) {
                float4 wa = *(const float4*)(V1 + (32 + mm) * 512 + jc0 * 4);
                float4 wb = *(const float4*)(V1 + (32 + mm) * 512 + jc1 * 4);
                float4 s4 = *(const float4*)&b2L[mm * 4];
                fma4(wa, s4, a0);
                fma4(wb, s4, a1);
            }
            bvv[l * 128 + jc0] = a0;
            bvv[l * 128 + jc1] = a1;
        }
    }
}

// ---------------- input node MLP (MFMA hi/lo GEMM2) + MFMA Ysrc/Ydst ----------------
__global__ __launch_bounds__(256) void k_h0(const float* __restrict__ x, const float* __restrict__ base1,
        const float* __restrict__ nw1, const u16* __restrict__ nw2h, const u16* __restrict__ nw2l,
        const float* __restrict__ nb2, const u16* __restrict__ Yw,
        float* __restrict__ hf, u16* __restrict__ Ysrc, u16* __restrict__ Ydst) {
    const int tid = threadIdx.x;
    const int w = tid >> 6, lane = tid & 63;
    const int cg = lane & 15, ng = lane >> 4;
    const int jc0 = w * 32 + cg * 2, jc1 = jc0 + 1;
    const int n0 = ng * 4;
    const int base = blockIdx.x * 16;
    const int lrow = lane & 15, quad = lane >> 4;
    __shared__ alignas(16) float xl[16][4];
    __shared__ alignas(16) u16 hih[16 * BPITCH], hil[16 * BPITCH];
    __shared__ alignas(16) u16 hb16[16 * BPITCH];
    if (tid < 48) { int n = tid / 3, cc = tid - n * 3; xl[n][cc] = x[(size_t)(base + n) * 3 + cc]; }
    __syncthreads();
    {
        float w0a = nw1[jc0], w0b = nw1[jc1];
        float w1a = nw1[128 + jc0], w1b = nw1[128 + jc1];
        float w2a = nw1[256 + jc0], w2b = nw1[256 + jc1];
        float ba = base1[jc0], bb = base1[jc1];
        #pragma unroll
        for (int n = 0; n < 4; ++n) {
            int row = n0 + n;
            float x0 = xl[row][0], x1 = xl[row][1], x2 = xl[row][2];
            float va = silu(ba + x0 * w0a + x1 * w1a + x2 * w2a);
            float vb = silu(bb + x0 * w0b + x1 * w1b + x2 * w2b);
            u32 hw = pack2(va, vb);
            *(u32*)&hih[row * BPITCH + jc0] = hw;
            *(u32*)&hil[row * BPITCH + jc0] = pack2(va - lo2f(hw), vb - hi2f(hw));
        }
    }
    __syncthreads();
    // GEMM2 (MFMA hi/lo): h = hid @ nw2 + nb2 -> hf (fp32) + hb16 (bf16)
    {
        bf16x8 ah[4], al[4];
        #pragma unroll
        for (int kc = 0; kc < 4; ++kc) {
            ah[kc] = *(const bf16x8*)(hih + lrow * BPITCH + kc * 32 + quad * 8);
            al[kc] = *(const bf16x8*)(hil + lrow * BPITCH + kc * 32 + quad * 8);
        }
        #pragma unroll
        for (int t = 0; t < 2; ++t) {
            int nt = w * 2 + t;
            f32x4 a4 = {0.f, 0.f, 0.f, 0.f};
            #pragma unroll
            for (int kc = 0; kc < 4; ++kc) {
                size_t o = (size_t)((kc * 8 + nt) * 512 + lane * 8);
                bf16x8 bh = *(const bf16x8*)(nw2h + o);
                bf16x8 bl = *(const bf16x8*)(nw2l + o);
                a4 = __builtin_amdgcn_mfma_f32_16x16x32_bf16(ah[kc], bh, a4, 0, 0, 0);
                a4 = __builtin_amdgcn_mfma_f32_16x16x32_bf16(al[kc], bh, a4, 0, 0, 0);
                a4 = __builtin_amdgcn_mfma_f32_16x16x32_bf16(ah[kc], bl, a4, 0, 0, 0);
            }
            int colC = nt * 16 + lrow;
            float bC = nb2[colC];
            #pragma unroll
            for (int r = 0; r < 4; ++r) {
                int R = quad * 4 + r;
                float v = a4[r] + bC;
                hf[(size_t)(base + R) * 128 + colC] = v;
                hb16[R * BPITCH + colC] = f2b(v);
            }
        }
    }
    __syncthreads();
    // MFMA Y-GEMMs: wave w -> mat = w>>1, nt-half = w&1
    {
        const int mat = w >> 1, half = w & 1;
        bf16x8 a[4];
        #pragma unroll
        for (int kc = 0; kc < 4; ++kc)
            a[kc] = *(const bf16x8*)(hb16 + lrow * BPITCH + kc * 32 + quad * 8);
        u16* dst = mat ? Ydst : Ysrc;
        #pragma unroll
        for (int t = 0; t < 4; ++t) {
            int nt = half * 4 + t;
            f32x4 a4 = {0.f, 0.f, 0.f, 0.f};
            #pragma unroll
            for (int kc = 0; kc < 4; ++kc) {
                bf16x8 b = *(const bf16x8*)(Yw + (size_t)(((mat * 4 + kc) * 8 + nt) * 512 + lane * 8));
                a4 = __builtin_amdgcn_mfma_f32_16x16x32_bf16(a[kc], b, a4, 0, 0, 0);
            }
            #pragma unroll
            for (int r = 0; r < 4; ++r)
                dst[(size_t)(base + quad * 4 + r) * 128 + nt * 16 + lrow] = f2b(a4[r]);
        }
    }
}

// ---------------- edge kernel (proven): 512 threads, bf16 sst, 2x8-row epilogue ----------------
__global__ __launch_bounds__(512, 8) void k_edge(
        const u16* __restrict__ Ysrc, const u16* __restrict__ Ydst,
        const float* __restrict__ x,
        const int* __restrict__ ssrc, const int* __restrict__ sdst,
        const u16* __restrict__ Wr,
        float* __restrict__ s_glob) {
    __shared__ alignas(16) u16 sst[128 * 72];   // [col][row] bf16, pitch 72
    __shared__ alignas(16) u16 ys[64 * 128];    // staged Ysrc rows
    __shared__ float rv[64];
    __shared__ alignas(16) int s_d[65];
    __shared__ int s_s[64];
    const int tid = threadIdx.x;
    const int e0 = blockIdx.x * 64;
    if (tid < 64) {
        int s = ssrc[e0 + tid], d = sdst[e0 + tid];
        s_s[tid] = s; s_d[tid] = d;
        float ddx = x[s * 3] - x[d * 3];
        float ddy = x[s * 3 + 1] - x[d * 3 + 1];
        rv[tid] = sqrtf(ddx * ddx + ddy * ddy + 1e-8f);
    } else if (tid == 64) {
        s_d[64] = -1;
    }
    __syncthreads();
    #pragma unroll
    for (int i = 0; i < 2; ++i) {
        int cch = tid + i * 512;
        int e = cch >> 4, part = cch & 15;
        *(uint4*)(ys + e * 128 + part * 8) = *(const uint4*)(Ysrc + (size_t)s_s[e] * 128 + part * 8);
    }
    const int w = tid >> 6, lane = tid & 63;
    const int m = w & 3, nh = w >> 2;
    const int lrow = lane & 15, quad = lane >> 4;
    float r = rv[m * 16 + lrow];
    union { bf16x8 v; u16 u[8]; } af;
    #pragma unroll
    for (int j = 0; j < 8; ++j) {
        int kk = quad * 8 + j;
        float v;
        if (kk < 16) {
            float dd = r - SQRT2 * (float)kk / 15.0f;
            v = __expf(-RBF_GAMMA * dd * dd);
        } else v = (kk == 16) ? 1.0f : 0.0f;
        af.u[j] = f2b(v);
    }
    {
        const u16* Bp = Wr + lane * 8;
        #pragma unroll
        for (int t = 0; t < 4; ++t) {
            int nt = nh * 4 + t;
            f32x4 a4 = {0.f, 0.f, 0.f, 0.f};
            bf16x8 b = *(const bf16x8*)(Bp + nt * 512);
            a4 = __builtin_amdgcn_mfma_f32_16x16x32_bf16(af.v, b, a4, 0, 0, 0);
            int col = nt * 16 + lrow;
            u32 lo = pack2(a4[0], a4[1]);
            u32 hi = pack2(a4[2], a4[3]);
            *(uint2*)(sst + col * 72 + m * 16 + quad * 4) = make_uint2(lo, hi);
        }
    }
    __syncthreads();
    {
        const int col = tid & 127, q = tid >> 7;
        const int r0 = q * 16;
        int nds[17];
        #pragma unroll
        for (int b = 0; b < 4; ++b)
            *(int4*)&nds[b * 4] = *(const int4*)&s_d[r0 + b * 4];
        nds[16] = s_d[r0 + 16];
        float a = 0.f;
        int cd = nds[0];
        float yd = b2f(Ydst[(size_t)cd * 128 + col]);
        #pragma unroll
        for (int h = 0; h < 2; ++h) {
            uint4 c0 = *(const uint4*)(sst + col * 72 + r0 + h * 8);
            float sv8[8];
            sv8[0] = lo2f(c0.x); sv8[1] = hi2f(c0.x);
            sv8[2] = lo2f(c0.y); sv8[3] = hi2f(c0.y);
            sv8[4] = lo2f(c0.z); sv8[5] = hi2f(c0.z);
            sv8[6] = lo2f(c0.w); sv8[7] = hi2f(c0.w);
            #pragma unroll
            for (int i = 0; i < 8; ++i) {
                int rr = r0 + h * 8 + i;
                int nd = nds[h * 8 + i + 1];
                float v = sv8[i] + b2f(ys[rr * 128 + col]) + yd;
                a += silu(v);
                bool last = (h == 1 && i == 7);
                if (last || nd != cd) {
                    atomicAdd(&s_glob[(size_t)cd * 128 + col], a);
                    a = 0.f;
                    if (!last && nd != cd)
                        yd = b2f(Ydst[(size_t)nd * 128 + col]);
                }
                cd = nd;
            }
        }
    }
}

// ---------------- node update: GEMM2' via MFMA (hi/lo bf16), GEMM3 via MFMA,
//                  MFMA Ysrc/Ydst (l<2) or fused output MLP (l==2) ----------------
__global__ __launch_bounds__(256) void k_node(float* __restrict__ s_glob, const int* __restrict__ row_ptr,
        float* __restrict__ hf,
        const u16* __restrict__ V1h, const u16* __restrict__ V1l,
        const u16* __restrict__ Mh, const u16* __restrict__ Ml,
        const u16* __restrict__ V2bf,
        const float* __restrict__ bv, const float* __restrict__ c1, const float* __restrict__ c2,
        const float* __restrict__ lng, const float* __restrict__ lnb,
        const u16* __restrict__ Yw,
        u16* __restrict__ Ysrc, u16* __restrict__ Ydst,
        const u16* __restrict__ ow1bf, const float* __restrict__ ob1,
        const float* __restrict__ ow2, const float* __restrict__ ob2,
        float* __restrict__ out) {
    const int tid = threadIdx.x;
    const int w = tid >> 6, lane = tid & 63;
    const int cg = lane & 15, ng = lane >> 4;
    const int jc0 = w * 32 + cg * 2, jc1 = jc0 + 1;
    const int n0 = ng * 4;
    const int base = blockIdx.x * 16;
    const int lrow = lane & 15, quad = lane >> 4;
    __shared__ alignas(16) float hv[16][PITCH];
    __shared__ alignas(16) float xs[16][PITCH];
    __shared__ alignas(16) u16 hvh[16 * BPITCH], hvl[16 * BPITCH];
    __shared__ alignas(16) u16 svh[16 * BPITCH], svl[16 * BPITCH];
    __shared__ alignas(16) u16 ybf[16 * BPITCH];
    __shared__ float mv[16][2];
    __shared__ int rp[17];

    if (tid < 17) rp[tid] = row_ptr[base + tid];
    {
        const float4* sg4 = (const float4*)(s_glob + (size_t)base * 128);
        float4* sg4w = (float4*)(s_glob + (size_t)base * 128);
        const float4* hg4 = (const float4*)(hf + (size_t)base * 128);
        for (int q = tid; q < 512; q += 256) {
            int row = q >> 5, part = q & 31;
            float4 s = sg4[q];
            float4 h = hg4[q];
            if (Yw != nullptr) sg4w[q] = make_float4(0.f, 0.f, 0.f, 0.f);
            *(float4*)&hv[row][part * 4] = h;
            u32 hw0 = pack2(h.x, h.y), hw1 = pack2(h.z, h.w);
            *(uint2*)&hvh[row * BPITCH + part * 4] = make_uint2(hw0, hw1);
            u32 hl0 = pack2(h.x - lo2f(hw0), h.y - hi2f(hw0));
            u32 hl1 = pack2(h.z - lo2f(hw1), h.w - hi2f(hw1));
            *(uint2*)&hvl[row * BPITCH + part * 4] = make_uint2(hl0, hl1);
            u32 sw0 = pack2(s.x, s.y), sw1 = pack2(s.z, s.w);
            *(uint2*)&svh[row * BPITCH + part * 4] = make_uint2(sw0, sw1);
            u32 sl0 = pack2(s.x - lo2f(sw0), s.y - hi2f(sw0));
            u32 sl1 = pack2(s.z - lo2f(sw1), s.w - hi2f(sw1));
            *(uint2*)&svl[row * BPITCH + part * 4] = make_uint2(sl0, sl1);
        }
    }
    __syncthreads();

    // ---- GEMM2' (MFMA, hi/lo bf16): u_pre = hv@V1a + sv@M + deg*bv + c1 ; uv = silu -> ybf ----
    {
        bf16x8 ahh[4], ahl[4], ash[4], asl[4];
        #pragma unroll
        for (int kc = 0; kc < 4; ++kc) {
            ahh[kc] = *(const bf16x8*)(hvh + lrow * BPITCH + kc * 32 + quad * 8);
            ahl[kc] = *(const bf16x8*)(hvl + lrow * BPITCH + kc * 32 + quad * 8);
            ash[kc] = *(const bf16x8*)(svh + lrow * BPITCH + kc * 32 + quad * 8);
            asl[kc] = *(const bf16x8*)(svl + lrow * BPITCH + kc * 32 + quad * 8);
        }
        float dg[4];
        #pragma unroll
        for (int r = 0; r < 4; ++r)
            dg[r] = (float)(rp[quad * 4 + r + 1] - rp[quad * 4 + r]);
        #pragma unroll
        for (int t = 0; t < 2; ++t) {
            int nt = w * 2 + t;
            f32x4 a4 = {0.f, 0.f, 0.f, 0.f};
            #pragma unroll
            for (int kc = 0; kc < 4; ++kc) {
                size_t o = (size_t)((kc * 8 + nt) * 512 + lane * 8);
                bf16x8 bh = *(const bf16x8*)(V1h + o);
                bf16x8 bl = *(const bf16x8*)(V1l + o);
                a4 = __builtin_amdgcn_mfma_f32_16x16x32_bf16(ahh[kc], bh, a4, 0, 0, 0);
                a4 = __builtin_amdgcn_mfma_f32_16x16x32_bf16(ahl[kc], bh, a4, 0, 0, 0);
                a4 = __builtin_amdgcn_mfma_f32_16x16x32_bf16(ahh[kc], bl, a4, 0, 0, 0);
                bf16x8 mh = *(const bf16x8*)(Mh + o);
                bf16x8 ml = *(const bf16x8*)(Ml + o);
                a4 = __builtin_amdgcn_mfma_f32_16x16x32_bf16(ash[kc], mh, a4, 0, 0, 0);
                a4 = __builtin_amdgcn_mfma_f32_16x16x32_bf16(asl[kc], mh, a4, 0, 0, 0);
                a4 = __builtin_amdgcn_mfma_f32_16x16x32_bf16(ash[kc], ml, a4, 0, 0, 0);
            }
            int colC = nt * 16 + lrow;
            float bvC = bv[colC], c1C = c1[colC];
            #pragma unroll
            for (int r = 0; r < 4; ++r) {
                float u = a4[r] + dg[r] * bvC + c1C;
                ybf[(quad * 4 + r) * BPITCH + colC] = f2b(silu(u));
            }
        }
    }
    __syncthreads();   // uv(bf16) ready
    // ---- GEMM3 (MFMA): o = uv @ V2 + c2 ; xj = hv + o -> xs (C-layout) ----
    {
        bf16x8 a[4];
        #pragma unroll
        for (int kc = 0; kc < 4; ++kc)
            a[kc] = *(const bf16x8*)(ybf + lrow * BPITCH + kc * 32 + quad * 8);
        #pragma unroll
        for (int t = 0; t < 2; ++t) {
            int nt = w * 2 + t;
            f32x4 a4 = {0.f, 0.f, 0.f, 0.f};
            #pragma unroll
            for (int kc = 0; kc < 4; ++kc) {
                bf16x8 b = *(const bf16x8*)(V2bf + (size_t)((kc * 8 + nt) * 512 + lane * 8));
                a4 = __builtin_amdgcn_mfma_f32_16x16x32_bf16(a[kc], b, a4, 0, 0, 0);
            }
            int colC = nt * 16 + lrow;
            float c2v = c2[colC];
            #pragma unroll
            for (int r = 0; r < 4; ++r) {
                int R = quad * 4 + r;
                xs[R][colC] = a4[r] + c2v + hv[R][colC];
            }
        }
    }
    __syncthreads();
    // ---- LN reduce ----
    {
        int row = tid >> 4, part = tid & 15;
        float4 a = *(const float4*)&xs[row][part * 8];
        float4 b = *(const float4*)&xs[row][part * 8 + 4];
        float s1 = a.x + a.y + a.z + a.w + b.x + b.y + b.z + b.w;
        float s2 = a.x * a.x + a.y * a.y + a.z * a.z + a.w * a.w
                 + b.x * b.x + b.y * b.y + b.z * b.z + b.w * b.w;
        #pragma unroll
        for (int mq = 1; mq < 16; mq <<= 1) {
            s1 += __shfl_xor(s1, mq, 64);
            s2 += __shfl_xor(s2, mq, 64);
        }
        if (part == 0) { mv[row][0] = s1; mv[row][1] = s2; }
    }
    __syncthreads();
    // ---- LN apply (writes y to bf16 tile; hf only when another layer follows) ----
    {
        float ga = lng[jc0], gb = lng[jc1];
        float bba = lnb[jc0], bbb = lnb[jc1];
        #pragma unroll
        for (int n = 0; n < 4; ++n) {
            int row = n0 + n;
            float mu = mv[row][0] * (1.0f / 128.0f);
            float var = mv[row][1] * (1.0f / 128.0f) - mu * mu;
            float rs = rsqrtf(var + 1e-5f);
            float y0 = (xs[row][jc0] - mu) * rs * ga + bba;
            float y1 = (xs[row][jc1] - mu) * rs * gb + bbb;
            if (Yw != nullptr)
                *(float2*)&hf[(size_t)(base + row) * 128 + jc0] = make_float2(y0, y1);
            *(u32*)&ybf[row * BPITCH + jc0] = pack2(y0, y1);
        }
    }
    if (Yw != nullptr) {
        __syncthreads();
        const int mat = w >> 1, half = w & 1;
        bf16x8 a[4];
        #pragma unroll
        for (int kc = 0; kc < 4; ++kc)
            a[kc] = *(const bf16x8*)(ybf + lrow * BPITCH + kc * 32 + quad * 8);
        u16* dst = mat ? Ydst : Ysrc;
        #pragma unroll
        for (int t = 0; t < 4; ++t) {
            int nt = half * 4 + t;
            f32x4 a4 = {0.f, 0.f, 0.f, 0.f};
            #pragma unroll
            for (int kc = 0; kc < 4; ++kc) {
                bf16x8 b = *(const bf16x8*)(Yw + (size_t)(((mat * 4 + kc) * 8 + nt) * 512 + lane * 8));
                a4 = __builtin_amdgcn_mfma_f32_16x16x32_bf16(a[kc], b, a4, 0, 0, 0);
            }
            #pragma unroll
            for (int r = 0; r < 4; ++r)
                dst[(size_t)(base + quad * 4 + r) * 128 + nt * 16 + lrow] = f2b(a4[r]);
        }
    } else {
        // ---- fused output MLP: hid2 = silu(y @ ow1 + ob1) -> hv ; out = hid2 @ ow2 + ob2 ----
        __syncthreads();
        {
            bf16x8 a[4];
            #pragma unroll
            for (int kc = 0; kc < 4; ++kc)
                a[kc] = *(const bf16x8*)(ybf + lrow * BPITCH + kc * 32 + quad * 8);
            #pragma unroll
            for (int t = 0; t < 2; ++t) {
                int nt = w * 2 + t;
                f32x4 a4 = {0.f, 0.f, 0.f, 0.f};
                #pragma unroll
                for (int kc = 0; kc < 4; ++kc) {
                    bf16x8 b = *(const bf16x8*)(ow1bf + (size_t)((kc * 8 + nt) * 512 + lane * 8));
                    a4 = __builtin_amdgcn_mfma_f32_16x16x32_bf16(a[kc], b, a4, 0, 0, 0);
                }
                int colC = nt * 16 + lrow;
                float b1v = ob1[colC];
                #pragma unroll
                for (int r = 0; r < 4; ++r)
                    hv[quad * 4 + r][colC] = silu(a4[r] + b1v);
            }
        }
        __syncthreads();
        {
            int row = tid >> 4, s = tid & 15;
            float p0 = 0.f, p1 = 0.f, p2 = 0.f;
            #pragma unroll
            for (int kk2 = 0; kk2 < 8; ++kk2) {
                int k = s * 8 + kk2;
                float h2 = hv[row][k];
                p0 = fmaf(h2, ow2[k * 3 + 0], p0);
                p1 = fmaf(h2, ow2[k * 3 + 1], p1);
                p2 = fmaf(h2, ow2[k * 3 + 2], p2);
            }
            #pragma unroll
            for (int mq = 1; mq < 16; mq <<= 1) {
                p0 += __shfl_xor(p0, mq, 64);
                p1 += __shfl_xor(p1, mq, 64);
                p2 += __shfl_xor(p2, mq, 64);
            }
            if (s == 0) {
                float* o = out + (size_t)(base + row) * 3;
                o[0] = p0 + ob2[0];
                o[1] = p1 + ob2[1];
                o[2] = p2 + ob2[2];
            }
        }
    }
}

extern "C" void kernel_launch(void* const* d_in, const int* in_sizes, int n_in,
                              void* d_out, int out_size, void* d_ws, size_t ws_size,
                              hipStream_t stream) {
    const float* x    = (const float*)d_in[0];
    const int* ei     = (const int*)d_in[1];
    const int* tptr   = (const int*)d_in[2];
    const float* tw1  = (const float*)d_in[3];
    const float* tb1  = (const float*)d_in[4];
    const float* tw2  = (const float*)d_in[5];
    const float* tb2  = (const float*)d_in[6];
    const float* nw1  = (const float*)d_in[7];
    const float* nb1  = (const float*)d_in[8];
    const float* nw2  = (const float*)d_in[9];
    const float* nb2  = (const float*)d_in[10];
    const float* pmw1 = (const float*)d_in[11];
    const float* pmb1 = (const float*)d_in[12];
    const float* pmw2 = (const float*)d_in[13];
    const float* pmb2 = (const float*)d_in[14];
    const float* phw1 = (const float*)d_in[15];
    const float* phb1 = (const float*)d_in[16];
    const float* phw2 = (const float*)d_in[17];
    const float* phb2 = (const float*)d_in[18];
    const float* lng  = (const float*)d_in[19];
    const float* lnb  = (const float*)d_in[20];
    const float* ow1  = (const float*)d_in[21];
    const float* ob1  = (const float*)d_in[22];
    const float* ow2  = (const float*)d_in[23];
    const float* ob2  = (const float*)d_in[24];
    float* out = (float*)d_out;

    char* wsp = (char*)d_ws;
    size_t off = 0;
    auto alloc = [&](size_t bytes) -> void* {
        void* p = wsp + off;
        off += (bytes + 255) & ~(size_t)255;
        return p;
    };
    int* hist    = (int*)alloc((size_t)NNODES * 4);
    int* cursor  = (int*)alloc((size_t)NNODES * 4);
    int* row_ptr = (int*)alloc((size_t)(NNODES + 1) * 4);
    int* ssrc    = (int*)alloc((size_t)NEDGES * 4);
    int* sdst    = (int*)alloc((size_t)NEDGES * 4);
    u16* Wr      = (u16*)alloc((size_t)3 * 8 * 64 * 8 * 2);
    u16* BF      = (u16*)alloc((size_t)18 * 16384 * 2);   // 6 Yw + 3 V2 + ow1 + 3 V1h + 3 V1l + nw2h + nw2l
    u16* Mf      = (u16*)alloc((size_t)6 * 16384 * 2);    // per layer M hi/lo frags
    float* base1 = (float*)alloc(128 * 4);
    float* V1p   = (float*)alloc((size_t)3 * 256 * 128 * 4);
    float* Mp    = (float*)alloc((size_t)3 * 128 * 128 * 4);
    float* bvv   = (float*)alloc((size_t)3 * 128 * 4);
    float* hf    = (float*)alloc((size_t)NNODES * 128 * 4);
    u16* Ysrc    = (u16*)alloc((size_t)NNODES * 128 * 2);
    u16* Ydst    = (u16*)alloc((size_t)NNODES * 128 * 2);
    float* s_glob= (float*)alloc((size_t)NNODES * 128 * 4);

    (void)hipMemsetAsync(hist, 0, (size_t)NNODES * 4, stream);
    k_hist<<<NEDGES / 256, 256, 0, stream>>>(ei, hist);
    k_scan<<<1, 1024, 0, stream>>>(hist, row_ptr, cursor);
    k_scatter<<<NEDGES / 256, 256, 0, stream>>>(ei, cursor, ssrc, sdst);

    PrepAll pa;
    pa.pmw1 = pmw1; pa.pmb1 = pmb1; pa.Wr = Wr;
    for (int l = 0; l < 3; ++l) {
        pa.bfs[l * 2 + 0] = pmw1 + (size_t)l * 34816;           // Y-src weights (W1 rows 0..127)
        pa.bfs[l * 2 + 1] = pmw1 + (size_t)l * 34816 + 16384;   // Y-dst weights (W1 rows 128..255)
        pa.bfs[6 + l] = phw2 + (size_t)l * 16384;               // V2
        pa.bfs[10 + l] = phw1 + (size_t)l * 32768;              // V1a hi (rows 0..127)
        pa.bfs[13 + l] = phw1 + (size_t)l * 32768;              // V1a lo
        pa.pks[l] = phw1 + (size_t)l * 32768;
        pa.pkd[l] = V1p + (size_t)l * 32768;
    }
    pa.bfs[9] = ow1;
    pa.bfs[16] = nw2;                                           // nw2 hi
    pa.bfs[17] = nw2;                                           // nw2 lo
    pa.BF = BF;
    pa.tptr = tptr; pa.tw1 = tw1; pa.tb1 = tb1; pa.tw2 = tw2; pa.tb2 = tb2;
    pa.nw1 = nw1; pa.nb1 = nb1; pa.base1 = base1;
    k_prep_all<<<535, 256, 0, stream>>>(pa);

    k_prep_m<<<dim3(9, 3), 256, 0, stream>>>(pmw2, pmb2, V1p, Mp, bvv);
    k_prep_mbf<<<48, 256, 0, stream>>>(Mp, Mf);

    k_h0<<<1250, 256, 0, stream>>>(x, base1, nw1,
            BF + (size_t)16 * 16384, BF + (size_t)17 * 16384, nb2, BF, hf, Ysrc, Ydst);

    (void)hipMemsetAsync(s_glob, 0, (size_t)NNODES * 128 * 4, stream);
    for (int l = 0; l < 3; ++l) {
        k_edge<<<NEDGES / 64, 512, 0, stream>>>(Ysrc, Ydst, x, ssrc, sdst,
                Wr + (size_t)l * 4096, s_glob);
        const u16* YwN = (l < 2) ? (BF + (size_t)(l + 1) * 32768) : nullptr;
        k_node<<<1250, 256, 0, stream>>>(s_glob, row_ptr, hf,
                BF + (size_t)(10 + l) * 16384, BF + (size_t)(13 + l) * 16384,
                Mf + (size_t)(l * 2) * 16384, Mf + (size_t)(l * 2 + 1) * 16384,
                BF + (size_t)(6 + l) * 16384,
                bvv + l * 128, phb1 + l * 128, phb2 + l * 128, lng + l * 128, lnb + l * 128,
                YwN, Ysrc, Ydst,
                BF + (size_t)9 * 16384, ob1, ow2, ob2, out);
    }
}

// Round 8
// 467.195 us; speedup vs baseline: 1.1889x; 1.0674x over previous
//
#include <hip/hip_runtime.h>

typedef unsigned short u16;
typedef unsigned int u32;

#define NNODES 20000
#define NEDGES 640000
// GAMMA = 1/(2*(sqrt(2)/15)^2) = 56.25 exactly
#define RBF_GAMMA 56.25f
#define SQRT2 1.4142135623730951f
#define PITCH 132    // fp32 LDS row pitch
#define BPITCH 136   // bf16 LDS row pitch (u16)

typedef __bf16 bf16x8 __attribute__((ext_vector_type(8)));
typedef __bf16 bf16x2 __attribute__((ext_vector_type(2)));
typedef float f32x4 __attribute__((ext_vector_type(4)));

__device__ __forceinline__ float b2f(u16 u) {
    union { float f; u32 i; } x; x.i = ((u32)u) << 16; return x.f;
}
__device__ __forceinline__ float hi2f(u32 w) {
    union { float f; u32 i; } x; x.i = w & 0xffff0000u; return x.f;
}
__device__ __forceinline__ float lo2f(u32 w) {
    union { float f; u32 i; } x; x.i = w << 16; return x.f;
}
__device__ __forceinline__ u16 f2b(float f) {
    union { float f; u32 i; } x; x.f = f;
    u32 r = (x.i + 0x7fffu + ((x.i >> 16) & 1u)) >> 16;
    return (u16)r;
}
// pack 2 fp32 -> 2 bf16 (RNE)
__device__ __forceinline__ u32 pack2(float a, float b) {
#if __has_builtin(__builtin_amdgcn_cvt_pk_bf16_f32)
    union { bf16x2 v; u32 u; } x;
    x.v = __builtin_amdgcn_cvt_pk_bf16_f32(a, b);
    return x.u;
#else
    return (u32)f2b(a) | ((u32)f2b(b) << 16);
#endif
}
__device__ __forceinline__ float silu(float v) {
    return v * __builtin_amdgcn_rcpf(1.0f + __expf(-v));
}
__device__ __forceinline__ void fma4(float4 w, float4 s, float& acc) {
    acc = fmaf(w.x, s.x, acc);
    acc = fmaf(w.y, s.y, acc);
    acc = fmaf(w.z, s.z, acc);
    acc = fmaf(w.w, s.w, acc);
}

// ---------------- sort by dst (counting sort) ----------------
__global__ __launch_bounds__(256) void k_hist(const int* __restrict__ ei, int* __restrict__ hist) {
    int e = blockIdx.x * 256 + threadIdx.x;
    atomicAdd(&hist[ei[NEDGES + e]], 1);
}

__global__ __launch_bounds__(1024) void k_scan(const int* __restrict__ hist,
                                               int* __restrict__ row_ptr,
                                               int* __restrict__ cursor) {
    __shared__ int psum[1024];
    int t = threadIdx.x;
    int base = t * 20;
    int s = 0;
    if (base < NNODES)
        for (int i = 0; i < 20; ++i) s += hist[base + i];
    psum[t] = s;
    __syncthreads();
    for (int off = 1; off < 1024; off <<= 1) {
        int v = (t >= off) ? psum[t - off] : 0;
        __syncthreads();
        psum[t] += v;
        __syncthreads();
    }
    int excl = psum[t] - s;
    if (base < NNODES) {
        int run = excl;
        for (int i = 0; i < 20; ++i) {
            row_ptr[base + i] = run;
            cursor[base + i] = run;
            run += hist[base + i];
        }
    }
    if (t == 1023) row_ptr[NNODES] = psum[1023];
}

__global__ __launch_bounds__(256) void k_scatter(const int* __restrict__ ei, int* __restrict__ cursor,
                                                 int* __restrict__ ssrc, int* __restrict__ sdst) {
    int e = blockIdx.x * 256 + threadIdx.x;
    int d = ei[NEDGES + e];
    int pos = atomicAdd(&cursor[d], 1);
    ssrc[pos] = ei[e];
    sdst[pos] = d;
}

// ---------------- merged prep: Wr frags + 18 bf16 B-frag mats + V1 pack + time MLP ----------------
// ids [0,1536): rbf-part W1 rows 256..271 + b1 -> Wr
// ids [1536,38400): 18 fp32[128][128] -> bf16 B-frag (hi: 0..12,16; lo: 13..15,17)
// ids [38400,136704): pack phw1 [256][128] -> [64][128][4] (3 layers)
// block 534: time embedding -> te -> base1
struct PrepAll {
    const float* pmw1; const float* pmb1; u16* Wr;
    const float* bfs[18]; u16* BF;
    const float* pks[3]; float* pkd[3];
    const int* tptr;
    const float* tw1; const float* tb1; const float* tw2; const float* tb2;
    const float* nw1; const float* nb1; float* base1;
};
__global__ __launch_bounds__(256) void k_prep_all(PrepAll pa) {
    const int tid = threadIdx.x;
    if (blockIdx.x == 534) {
        __shared__ float emb[128], hid[128], te[128];
        int j = tid;
        if (j < 128) {
            int raw = pa.tptr[0];
            float tv;
            if (raw >= 0 && raw < (1 << 24)) tv = (float)raw;
            else tv = __int_as_float(raw);
            float fr = expf(-9.210340371976184f * (float)(j & 63) / 63.0f);
            float a = tv * fr;
            emb[j] = (j < 64) ? sinf(a) : cosf(a);
        }
        __syncthreads();
        if (j < 128) {
            float acc = pa.tb1[j];
            for (int k = 0; k < 128; ++k) acc += emb[k] * pa.tw1[k * 128 + j];
            hid[j] = silu(acc);
        }
        __syncthreads();
        if (j < 128) {
            float acc = pa.tb2[j];
            for (int k = 0; k < 128; ++k) acc += hid[k] * pa.tw2[k * 128 + j];
            te[j] = acc;
        }
        __syncthreads();
        if (j < 128) {
            float acc = pa.nb1[j];
            for (int k = 0; k < 128; ++k) acc += te[k] * pa.nw1[(3 + k) * 128 + j];
            pa.base1[j] = acc;
        }
        return;
    }
    int id = blockIdx.x * 256 + tid;
    if (id < 1536) {
        int l = id / 512; int r = id - l * 512;
        int nt = r >> 6, lane = r & 63;
        int col = nt * 16 + (lane & 15);
        alignas(16) u16 tmp[8];
        #pragma unroll
        for (int jj = 0; jj < 8; ++jj) {
            int kk = (lane >> 4) * 8 + jj;
            float v = 0.f;
            if (kk < 16) v = pa.pmw1[l * 34816 + (256 + kk) * 128 + col];
            else if (kk == 16) v = pa.pmb1[l * 128 + col];
            tmp[jj] = f2b(v);
        }
        *(uint4*)(pa.Wr + (size_t)id * 8) = *(const uint4*)tmp;
    } else if (id < 38400) {
        int id2 = id - 1536;
        int mat = id2 >> 11;
        bool lomode = (mat >= 13 && mat != 16);
        int r = id2 & 2047;
        int kc = r >> 9;
        int r2 = r & 511;
        int nt = r2 >> 6, lane = r2 & 63;
        int col = nt * 16 + (lane & 15);
        int kb = kc * 32 + (lane >> 4) * 8;
        const float* src = pa.bfs[mat];
        alignas(16) u16 tmp[8];
        #pragma unroll
        for (int jj = 0; jj < 8; ++jj) {
            float v = src[(kb + jj) * 128 + col];
            u16 h = f2b(v);
            tmp[jj] = lomode ? f2b(v - b2f(h)) : h;
        }
        *(uint4*)(pa.BF + (size_t)id2 * 8) = *(const uint4*)tmp;
    } else {
        int id2 = id - 38400;            // < 98304
        int m = id2 >> 15, r = id2 & 32767;
        int k = r >> 7, j2 = r & 127;
        pa.pkd[m][(k >> 2) * 512 + j2 * 4 + (k & 3)] = pa.pks[m][r];
    }
}

// ---------------- prep: M = W2 @ V1b -> hi/lo bf16 frags directly, and bv = b2 @ V1b ----------------
__global__ __launch_bounds__(256) void k_prep_m(const float* __restrict__ pmw2,
        const float* __restrict__ pmb2, const float* __restrict__ V1p,
        u16* __restrict__ Mf, float* __restrict__ bvv) {
    const int l = blockIdx.y, bx = blockIdx.x;
    const float* V1 = V1p + (size_t)l * 32768;
    const int tid = threadIdx.x;
    const int w = tid >> 6, lane = tid & 63;
    const int cg = lane & 15, ng = lane >> 4;
    const int jc0 = w * 32 + cg * 2, jc1 = jc0 + 1;
    __shared__ alignas(16) float W2L[16][PITCH];
    __shared__ float b2L[128];
    if (bx < 8) {
        const float4* src = (const float4*)(pmw2 + (size_t)l * 16384 + bx * 16 * 128);
        for (int q = tid; q < 512; q += 256) {
            int row = q >> 5, part = q & 31;
            *(float4*)&W2L[row][part * 4] = src[q];
        }
        __syncthreads();
        int r0 = ng * 4;
        float acc[4][2];
        #pragma unroll
        for (int n = 0; n < 4; ++n) { acc[n][0] = 0.f; acc[n][1] = 0.f; }
        for (int mm = 0; mm < 32; ++mm) {
            float4 wa = *(const float4*)(V1 + (32 + mm) * 512 + jc0 * 4);
            float4 wb = *(const float4*)(V1 + (32 + mm) * 512 + jc1 * 4);
            #pragma unroll
            for (int n = 0; n < 4; ++n) {
                float4 s4 = *(const float4*)&W2L[r0 + n][mm * 4];
                fma4(wa, s4, acc[n][0]);
                fma4(wb, s4, acc[n][1]);
            }
        }
        u16* Mfh = Mf + (size_t)(l * 2) * 16384;
        u16* Mfl = Mfh + 16384;
        #pragma unroll
        for (int n = 0; n < 4; ++n) {
            int kg = bx * 16 + r0 + n;
            int kc = kg >> 5, klane = (kg >> 3) & 3, j = kg & 7;
            #pragma unroll
            for (int c = 0; c < 2; ++c) {
                int col = c ? jc1 : jc0;
                float v = acc[n][c];
                u16 h = f2b(v);
                // element offset = (kc*8 + nt)*512 + lane*8 + j, lane = 16*klane + (col&15)
                size_t idx = (size_t)((kc * 8 + (col >> 4)) * 512
                                      + ((col & 15) + 16 * klane) * 8 + j);
                Mfh[idx] = h;
                Mfl[idx] = f2b(v - b2f(h));
            }
        }
    } else {
        if (tid < 128) b2L[tid] = pmb2[l * 128 + tid];
        __syncthreads();
        if (ng == 0) {
            float a0 = 0.f, a1 = 0.f;
            for (int mm = 0; mm < 32; ++mm) {
                float4 wa = *(const float4*)(V1 + (32 + mm) * 512 + jc0 * 4);
                float4 wb = *(const float4*)(V1 + (32 + mm) * 512 + jc1 * 4);
                float4 s4 = *(const float4*)&b2L[mm * 4];
                fma4(wa, s4, a0);
                fma4(wb, s4, a1);
            }
            bvv[l * 128 + jc0] = a0;
            bvv[l * 128 + jc1] = a1;
        }
    }
}

// ---------------- input node MLP (MFMA hi/lo GEMM2) + MFMA Ysrc/Ydst ----------------
__global__ __launch_bounds__(256) void k_h0(const float* __restrict__ x, const float* __restrict__ base1,
        const float* __restrict__ nw1, const u16* __restrict__ nw2h, const u16* __restrict__ nw2l,
        const float* __restrict__ nb2, const u16* __restrict__ Yw,
        float* __restrict__ hf, u16* __restrict__ Ysrc, u16* __restrict__ Ydst) {
    const int tid = threadIdx.x;
    const int w = tid >> 6, lane = tid & 63;
    const int cg = lane & 15, ng = lane >> 4;
    const int jc0 = w * 32 + cg * 2, jc1 = jc0 + 1;
    const int n0 = ng * 4;
    const int base = blockIdx.x * 16;
    const int lrow = lane & 15, quad = lane >> 4;
    __shared__ alignas(16) float xl[16][4];
    __shared__ alignas(16) u16 hih[16 * BPITCH], hil[16 * BPITCH];
    __shared__ alignas(16) u16 hb16[16 * BPITCH];
    if (tid < 48) { int n = tid / 3, cc = tid - n * 3; xl[n][cc] = x[(size_t)(base + n) * 3 + cc]; }
    __syncthreads();
    {
        float w0a = nw1[jc0], w0b = nw1[jc1];
        float w1a = nw1[128 + jc0], w1b = nw1[128 + jc1];
        float w2a = nw1[256 + jc0], w2b = nw1[256 + jc1];
        float ba = base1[jc0], bb = base1[jc1];
        #pragma unroll
        for (int n = 0; n < 4; ++n) {
            int row = n0 + n;
            float x0 = xl[row][0], x1 = xl[row][1], x2 = xl[row][2];
            float va = silu(ba + x0 * w0a + x1 * w1a + x2 * w2a);
            float vb = silu(bb + x0 * w0b + x1 * w1b + x2 * w2b);
            u32 hw = pack2(va, vb);
            *(u32*)&hih[row * BPITCH + jc0] = hw;
            *(u32*)&hil[row * BPITCH + jc0] = pack2(va - lo2f(hw), vb - hi2f(hw));
        }
    }
    __syncthreads();
    // GEMM2 (MFMA hi/lo): h = hid @ nw2 + nb2 -> hf (fp32) + hb16 (bf16)
    {
        bf16x8 ah[4], al[4];
        #pragma unroll
        for (int kc = 0; kc < 4; ++kc) {
            ah[kc] = *(const bf16x8*)(hih + lrow * BPITCH + kc * 32 + quad * 8);
            al[kc] = *(const bf16x8*)(hil + lrow * BPITCH + kc * 32 + quad * 8);
        }
        #pragma unroll
        for (int t = 0; t < 2; ++t) {
            int nt = w * 2 + t;
            f32x4 a4 = {0.f, 0.f, 0.f, 0.f};
            #pragma unroll
            for (int kc = 0; kc < 4; ++kc) {
                size_t o = (size_t)((kc * 8 + nt) * 512 + lane * 8);
                bf16x8 bh = *(const bf16x8*)(nw2h + o);
                bf16x8 bl = *(const bf16x8*)(nw2l + o);
                a4 = __builtin_amdgcn_mfma_f32_16x16x32_bf16(ah[kc], bh, a4, 0, 0, 0);
                a4 = __builtin_amdgcn_mfma_f32_16x16x32_bf16(al[kc], bh, a4, 0, 0, 0);
                a4 = __builtin_amdgcn_mfma_f32_16x16x32_bf16(ah[kc], bl, a4, 0, 0, 0);
            }
            int colC = nt * 16 + lrow;
            float bC = nb2[colC];
            #pragma unroll
            for (int r = 0; r < 4; ++r) {
                int R = quad * 4 + r;
                float v = a4[r] + bC;
                hf[(size_t)(base + R) * 128 + colC] = v;
                hb16[R * BPITCH + colC] = f2b(v);
            }
        }
    }
    __syncthreads();
    // MFMA Y-GEMMs: wave w -> mat = w>>1, nt-half = w&1
    {
        const int mat = w >> 1, half = w & 1;
        bf16x8 a[4];
        #pragma unroll
        for (int kc = 0; kc < 4; ++kc)
            a[kc] = *(const bf16x8*)(hb16 + lrow * BPITCH + kc * 32 + quad * 8);
        u16* dst = mat ? Ydst : Ysrc;
        #pragma unroll
        for (int t = 0; t < 4; ++t) {
            int nt = half * 4 + t;
            f32x4 a4 = {0.f, 0.f, 0.f, 0.f};
            #pragma unroll
            for (int kc = 0; kc < 4; ++kc) {
                bf16x8 b = *(const bf16x8*)(Yw + (size_t)(((mat * 4 + kc) * 8 + nt) * 512 + lane * 8));
                a4 = __builtin_amdgcn_mfma_f32_16x16x32_bf16(a[kc], b, a4, 0, 0, 0);
            }
            #pragma unroll
            for (int r = 0; r < 4; ++r)
                dst[(size_t)(base + quad * 4 + r) * 128 + nt * 16 + lrow] = f2b(a4[r]);
        }
    }
}

// ---------------- edge kernel (proven): 512 threads, bf16 sst, 2x8-row epilogue ----------------
__global__ __launch_bounds__(512, 8) void k_edge(
        const u16* __restrict__ Ysrc, const u16* __restrict__ Ydst,
        const float* __restrict__ x,
        const int* __restrict__ ssrc, const int* __restrict__ sdst,
        const u16* __restrict__ Wr,
        float* __restrict__ s_glob) {
    __shared__ alignas(16) u16 sst[128 * 72];   // [col][row] bf16, pitch 72
    __shared__ alignas(16) u16 ys[64 * 128];    // staged Ysrc rows
    __shared__ float rv[64];
    __shared__ alignas(16) int s_d[65];
    __shared__ int s_s[64];
    const int tid = threadIdx.x;
    const int e0 = blockIdx.x * 64;
    if (tid < 64) {
        int s = ssrc[e0 + tid], d = sdst[e0 + tid];
        s_s[tid] = s; s_d[tid] = d;
        float ddx = x[s * 3] - x[d * 3];
        float ddy = x[s * 3 + 1] - x[d * 3 + 1];
        rv[tid] = sqrtf(ddx * ddx + ddy * ddy + 1e-8f);
    } else if (tid == 64) {
        s_d[64] = -1;
    }
    __syncthreads();
    #pragma unroll
    for (int i = 0; i < 2; ++i) {
        int cch = tid + i * 512;
        int e = cch >> 4, part = cch & 15;
        *(uint4*)(ys + e * 128 + part * 8) = *(const uint4*)(Ysrc + (size_t)s_s[e] * 128 + part * 8);
    }
    const int w = tid >> 6, lane = tid & 63;
    const int m = w & 3, nh = w >> 2;
    const int lrow = lane & 15, quad = lane >> 4;
    float r = rv[m * 16 + lrow];
    union { bf16x8 v; u16 u[8]; } af;
    #pragma unroll
    for (int j = 0; j < 8; ++j) {
        int kk = quad * 8 + j;
        float v;
        if (kk < 16) {
            float dd = r - SQRT2 * (float)kk / 15.0f;
            v = __expf(-RBF_GAMMA * dd * dd);
        } else v = (kk == 16) ? 1.0f : 0.0f;
        af.u[j] = f2b(v);
    }
    {
        const u16* Bp = Wr + lane * 8;
        #pragma unroll
        for (int t = 0; t < 4; ++t) {
            int nt = nh * 4 + t;
            f32x4 a4 = {0.f, 0.f, 0.f, 0.f};
            bf16x8 b = *(const bf16x8*)(Bp + nt * 512);
            a4 = __builtin_amdgcn_mfma_f32_16x16x32_bf16(af.v, b, a4, 0, 0, 0);
            int col = nt * 16 + lrow;
            u32 lo = pack2(a4[0], a4[1]);
            u32 hi = pack2(a4[2], a4[3]);
            *(uint2*)(sst + col * 72 + m * 16 + quad * 4) = make_uint2(lo, hi);
        }
    }
    __syncthreads();
    {
        const int col = tid & 127, q = tid >> 7;
        const int r0 = q * 16;
        int nds[17];
        #pragma unroll
        for (int b = 0; b < 4; ++b)
            *(int4*)&nds[b * 4] = *(const int4*)&s_d[r0 + b * 4];
        nds[16] = s_d[r0 + 16];
        float a = 0.f;
        int cd = nds[0];
        float yd = b2f(Ydst[(size_t)cd * 128 + col]);
        #pragma unroll
        for (int h = 0; h < 2; ++h) {
            uint4 c0 = *(const uint4*)(sst + col * 72 + r0 + h * 8);
            float sv8[8];
            sv8[0] = lo2f(c0.x); sv8[1] = hi2f(c0.x);
            sv8[2] = lo2f(c0.y); sv8[3] = hi2f(c0.y);
            sv8[4] = lo2f(c0.z); sv8[5] = hi2f(c0.z);
            sv8[6] = lo2f(c0.w); sv8[7] = hi2f(c0.w);
            #pragma unroll
            for (int i = 0; i < 8; ++i) {
                int rr = r0 + h * 8 + i;
                int nd = nds[h * 8 + i + 1];
                float v = sv8[i] + b2f(ys[rr * 128 + col]) + yd;
                float e = __expf(-v);
                a = fmaf(v, __builtin_amdgcn_rcpf(1.0f + e), a);
                bool last = (h == 1 && i == 7);
                if (last || nd != cd) {
                    atomicAdd(&s_glob[(size_t)cd * 128 + col], a);
                    a = 0.f;
                    if (!last && nd != cd)
                        yd = b2f(Ydst[(size_t)nd * 128 + col]);
                }
                cd = nd;
            }
        }
    }
}

// ---------------- node update: GEMM2' via MFMA (hi/lo bf16), GEMM3 via MFMA,
//                  MFMA Ysrc/Ydst (l<2) or fused output MLP (l==2)
//                  LDS-aliased: ybf over hvh, xs over svh/svl (25.5 KB -> 6 blocks/CU) ----------------
__global__ __launch_bounds__(256) void k_node(float* __restrict__ s_glob, const int* __restrict__ row_ptr,
        float* __restrict__ hf,
        const u16* __restrict__ V1h, const u16* __restrict__ V1l,
        const u16* __restrict__ Mh, const u16* __restrict__ Ml,
        const u16* __restrict__ V2bf,
        const float* __restrict__ bv, const float* __restrict__ c1, const float* __restrict__ c2,
        const float* __restrict__ lng, const float* __restrict__ lnb,
        const u16* __restrict__ Yw,
        u16* __restrict__ Ysrc, u16* __restrict__ Ydst,
        const u16* __restrict__ ow1bf, const float* __restrict__ ob1,
        const float* __restrict__ ow2, const float* __restrict__ ob2,
        float* __restrict__ out) {
    const int tid = threadIdx.x;
    const int w = tid >> 6, lane = tid & 63;
    const int cg = lane & 15, ng = lane >> 4;
    const int jc0 = w * 32 + cg * 2, jc1 = jc0 + 1;
    const int n0 = ng * 4;
    const int base = blockIdx.x * 16;
    const int lrow = lane & 15, quad = lane >> 4;
    __shared__ alignas(16) float hv[16][PITCH];          // 8448 B
    __shared__ alignas(16) u16 T[4 * 16 * BPITCH];       // 17408 B, aliased below
    __shared__ float mv[16][2];
    __shared__ int rp[17];
    u16* hvh = T;
    u16* hvl = T + 16 * BPITCH;
    u16* svh = T + 2 * 16 * BPITCH;
    u16* svl = T + 3 * 16 * BPITCH;
    u16* ybf = T;                                        // aliases hvh (dead after reg loads)
    float (*xs)[PITCH] = (float (*)[PITCH])svh;          // aliases svh+svl (8448 <= 8704)

    if (tid < 17) rp[tid] = row_ptr[base + tid];
    {
        const float4* sg4 = (const float4*)(s_glob + (size_t)base * 128);
        float4* sg4w = (float4*)(s_glob + (size_t)base * 128);
        const float4* hg4 = (const float4*)(hf + (size_t)base * 128);
        for (int q = tid; q < 512; q += 256) {
            int row = q >> 5, part = q & 31;
            float4 s = sg4[q];
            float4 h = hg4[q];
            if (Yw != nullptr) sg4w[q] = make_float4(0.f, 0.f, 0.f, 0.f);
            *(float4*)&hv[row][part * 4] = h;
            u32 hw0 = pack2(h.x, h.y), hw1 = pack2(h.z, h.w);
            *(uint2*)&hvh[row * BPITCH + part * 4] = make_uint2(hw0, hw1);
            u32 hl0 = pack2(h.x - lo2f(hw0), h.y - hi2f(hw0));
            u32 hl1 = pack2(h.z - lo2f(hw1), h.w - hi2f(hw1));
            *(uint2*)&hvl[row * BPITCH + part * 4] = make_uint2(hl0, hl1);
            u32 sw0 = pack2(s.x, s.y), sw1 = pack2(s.z, s.w);
            *(uint2*)&svh[row * BPITCH + part * 4] = make_uint2(sw0, sw1);
            u32 sl0 = pack2(s.x - lo2f(sw0), s.y - hi2f(sw0));
            u32 sl1 = pack2(s.z - lo2f(sw1), s.w - hi2f(sw1));
            *(uint2*)&svl[row * BPITCH + part * 4] = make_uint2(sl0, sl1);
        }
    }
    __syncthreads();

    // ---- GEMM2' (MFMA, hi/lo bf16): u_pre = hv@V1a + sv@M + deg*bv + c1 ; uv = silu -> ybf ----
    {
        bf16x8 ahh[4], ahl[4], ash[4], asl[4];
        #pragma unroll
        for (int kc = 0; kc < 4; ++kc) {
            ahh[kc] = *(const bf16x8*)(hvh + lrow * BPITCH + kc * 32 + quad * 8);
            ahl[kc] = *(const bf16x8*)(hvl + lrow * BPITCH + kc * 32 + quad * 8);
            ash[kc] = *(const bf16x8*)(svh + lrow * BPITCH + kc * 32 + quad * 8);
            asl[kc] = *(const bf16x8*)(svl + lrow * BPITCH + kc * 32 + quad * 8);
        }
        float dg[4];
        #pragma unroll
        for (int r = 0; r < 4; ++r)
            dg[r] = (float)(rp[quad * 4 + r + 1] - rp[quad * 4 + r]);
        __syncthreads();   // all reg loads done before ybf (aliases hvh) is written
        #pragma unroll
        for (int t = 0; t < 2; ++t) {
            int nt = w * 2 + t;
            f32x4 a4 = {0.f, 0.f, 0.f, 0.f};
            #pragma unroll
            for (int kc = 0; kc < 4; ++kc) {
                size_t o = (size_t)((kc * 8 + nt) * 512 + lane * 8);
                bf16x8 bh = *(const bf16x8*)(V1h + o);
                bf16x8 bl = *(const bf16x8*)(V1l + o);
                a4 = __builtin_amdgcn_mfma_f32_16x16x32_bf16(ahh[kc], bh, a4, 0, 0, 0);
                a4 = __builtin_amdgcn_mfma_f32_16x16x32_bf16(ahl[kc], bh, a4, 0, 0, 0);
                a4 = __builtin_amdgcn_mfma_f32_16x16x32_bf16(ahh[kc], bl, a4, 0, 0, 0);
                bf16x8 mh = *(const bf16x8*)(Mh + o);
                bf16x8 ml = *(const bf16x8*)(Ml + o);
                a4 = __builtin_amdgcn_mfma_f32_16x16x32_bf16(ash[kc], mh, a4, 0, 0, 0);
                a4 = __builtin_amdgcn_mfma_f32_16x16x32_bf16(asl[kc], mh, a4, 0, 0, 0);
                a4 = __builtin_amdgcn_mfma_f32_16x16x32_bf16(ash[kc], ml, a4, 0, 0, 0);
            }
            int colC = nt * 16 + lrow;
            float bvC = bv[colC], c1C = c1[colC];
            #pragma unroll
            for (int r = 0; r < 4; ++r) {
                float u = a4[r] + dg[r] * bvC + c1C;
                ybf[(quad * 4 + r) * BPITCH + colC] = f2b(silu(u));
            }
        }
    }
    __syncthreads();   // uv(bf16) ready; svh/svl dead -> xs region free
    // ---- GEMM3 (MFMA): o = uv @ V2 + c2 ; xj = hv + o -> xs (C-layout) ----
    {
        bf16x8 a[4];
        #pragma unroll
        for (int kc = 0; kc < 4; ++kc)
            a[kc] = *(const bf16x8*)(ybf + lrow * BPITCH + kc * 32 + quad * 8);
        #pragma unroll
        for (int t = 0; t < 2; ++t) {
            int nt = w * 2 + t;
            f32x4 a4 = {0.f, 0.f, 0.f, 0.f};
            #pragma unroll
            for (int kc = 0; kc < 4; ++kc) {
                bf16x8 b = *(const bf16x8*)(V2bf + (size_t)((kc * 8 + nt) * 512 + lane * 8));
                a4 = __builtin_amdgcn_mfma_f32_16x16x32_bf16(a[kc], b, a4, 0, 0, 0);
            }
            int colC = nt * 16 + lrow;
            float c2v = c2[colC];
            #pragma unroll
            for (int r = 0; r < 4; ++r) {
                int R = quad * 4 + r;
                xs[R][colC] = a4[r] + c2v + hv[R][colC];
            }
        }
    }
    __syncthreads();
    // ---- LN reduce ----
    {
        int row = tid >> 4, part = tid & 15;
        float4 a = *(const float4*)&xs[row][part * 8];
        float4 b = *(const float4*)&xs[row][part * 8 + 4];
        float s1 = a.x + a.y + a.z + a.w + b.x + b.y + b.z + b.w;
        float s2 = a.x * a.x + a.y * a.y + a.z * a.z + a.w * a.w
                 + b.x * b.x + b.y * b.y + b.z * b.z + b.w * b.w;
        #pragma unroll
        for (int mq = 1; mq < 16; mq <<= 1) {
            s1 += __shfl_xor(s1, mq, 64);
            s2 += __shfl_xor(s2, mq, 64);
        }
        if (part == 0) { mv[row][0] = s1; mv[row][1] = s2; }
    }
    __syncthreads();
    // ---- LN apply (writes y to bf16 tile; hf only when another layer follows) ----
    {
        float ga = lng[jc0], gb = lng[jc1];
        float bba = lnb[jc0], bbb = lnb[jc1];
        #pragma unroll
        for (int n = 0; n < 4; ++n) {
            int row = n0 + n;
            float mu = mv[row][0] * (1.0f / 128.0f);
            float var = mv[row][1] * (1.0f / 128.0f) - mu * mu;
            float rs = rsqrtf(var + 1e-5f);
            float y0 = (xs[row][jc0] - mu) * rs * ga + bba;
            float y1 = (xs[row][jc1] - mu) * rs * gb + bbb;
            if (Yw != nullptr)
                *(float2*)&hf[(size_t)(base + row) * 128 + jc0] = make_float2(y0, y1);
            *(u32*)&ybf[row * BPITCH + jc0] = pack2(y0, y1);
        }
    }
    if (Yw != nullptr) {
        __syncthreads();
        const int mat = w >> 1, half = w & 1;
        bf16x8 a[4];
        #pragma unroll
        for (int kc = 0; kc < 4; ++kc)
            a[kc] = *(const bf16x8*)(ybf + lrow * BPITCH + kc * 32 + quad * 8);
        u16* dst = mat ? Ydst : Ysrc;
        #pragma unroll
        for (int t = 0; t < 4; ++t) {
            int nt = half * 4 + t;
            f32x4 a4 = {0.f, 0.f, 0.f, 0.f};
            #pragma unroll
            for (int kc = 0; kc < 4; ++kc) {
                bf16x8 b = *(const bf16x8*)(Yw + (size_t)(((mat * 4 + kc) * 8 + nt) * 512 + lane * 8));
                a4 = __builtin_amdgcn_mfma_f32_16x16x32_bf16(a[kc], b, a4, 0, 0, 0);
            }
            #pragma unroll
            for (int r = 0; r < 4; ++r)
                dst[(size_t)(base + quad * 4 + r) * 128 + nt * 16 + lrow] = f2b(a4[r]);
        }
    } else {
        // ---- fused output MLP: hid2 = silu(y @ ow1 + ob1) -> hv ; out = hid2 @ ow2 + ob2 ----
        __syncthreads();
        {
            bf16x8 a[4];
            #pragma unroll
            for (int kc = 0; kc < 4; ++kc)
                a[kc] = *(const bf16x8*)(ybf + lrow * BPITCH + kc * 32 + quad * 8);
            #pragma unroll
            for (int t = 0; t < 2; ++t) {
                int nt = w * 2 + t;
                f32x4 a4 = {0.f, 0.f, 0.f, 0.f};
                #pragma unroll
                for (int kc = 0; kc < 4; ++kc) {
                    bf16x8 b = *(const bf16x8*)(ow1bf + (size_t)((kc * 8 + nt) * 512 + lane * 8));
                    a4 = __builtin_amdgcn_mfma_f32_16x16x32_bf16(a[kc], b, a4, 0, 0, 0);
                }
                int colC = nt * 16 + lrow;
                float b1v = ob1[colC];
                #pragma unroll
                for (int r = 0; r < 4; ++r)
                    hv[quad * 4 + r][colC] = silu(a4[r] + b1v);
            }
        }
        __syncthreads();
        {
            int row = tid >> 4, s = tid & 15;
            float p0 = 0.f, p1 = 0.f, p2 = 0.f;
            #pragma unroll
            for (int kk2 = 0; kk2 < 8; ++kk2) {
                int k = s * 8 + kk2;
                float h2 = hv[row][k];
                p0 = fmaf(h2, ow2[k * 3 + 0], p0);
                p1 = fmaf(h2, ow2[k * 3 + 1], p1);
                p2 = fmaf(h2, ow2[k * 3 + 2], p2);
            }
            #pragma unroll
            for (int mq = 1; mq < 16; mq <<= 1) {
                p0 += __shfl_xor(p0, mq, 64);
                p1 += __shfl_xor(p1, mq, 64);
                p2 += __shfl_xor(p2, mq, 64);
            }
            if (s == 0) {
                float* o = out + (size_t)(base + row) * 3;
                o[0] = p0 + ob2[0];
                o[1] = p1 + ob2[1];
                o[2] = p2 + ob2[2];
            }
        }
    }
}

extern "C" void kernel_launch(void* const* d_in, const int* in_sizes, int n_in,
                              void* d_out, int out_size, void* d_ws, size_t ws_size,
                              hipStream_t stream) {
    const float* x    = (const float*)d_in[0];
    const int* ei     = (const int*)d_in[1];
    const int* tptr   = (const int*)d_in[2];
    const float* tw1  = (const float*)d_in[3];
    const float* tb1  = (const float*)d_in[4];
    const float* tw2  = (const float*)d_in[5];
    const float* tb2  = (const float*)d_in[6];
    const float* nw1  = (const float*)d_in[7];
    const float* nb1  = (const float*)d_in[8];
    const float* nw2  = (const float*)d_in[9];
    const float* nb2  = (const float*)d_in[10];
    const float* pmw1 = (const float*)d_in[11];
    const float* pmb1 = (const float*)d_in[12];
    const float* pmw2 = (const float*)d_in[13];
    const float* pmb2 = (const float*)d_in[14];
    const float* phw1 = (const float*)d_in[15];
    const float* phb1 = (const float*)d_in[16];
    const float* phw2 = (const float*)d_in[17];
    const float* phb2 = (const float*)d_in[18];
    const float* lng  = (const float*)d_in[19];
    const float* lnb  = (const float*)d_in[20];
    const float* ow1  = (const float*)d_in[21];
    const float* ob1  = (const float*)d_in[22];
    const float* ow2  = (const float*)d_in[23];
    const float* ob2  = (const float*)d_in[24];
    float* out = (float*)d_out;

    char* wsp = (char*)d_ws;
    size_t off = 0;
    auto alloc = [&](size_t bytes) -> void* {
        void* p = wsp + off;
        off += (bytes + 255) & ~(size_t)255;
        return p;
    };
    int* hist    = (int*)alloc((size_t)NNODES * 4);
    int* cursor  = (int*)alloc((size_t)NNODES * 4);
    int* row_ptr = (int*)alloc((size_t)(NNODES + 1) * 4);
    int* ssrc    = (int*)alloc((size_t)NEDGES * 4);
    int* sdst    = (int*)alloc((size_t)NEDGES * 4);
    u16* Wr      = (u16*)alloc((size_t)3 * 8 * 64 * 8 * 2);
    u16* BF      = (u16*)alloc((size_t)18 * 16384 * 2);   // 6 Yw + 3 V2 + ow1 + 3 V1h + 3 V1l + nw2h + nw2l
    u16* Mf      = (u16*)alloc((size_t)6 * 16384 * 2);    // per layer M hi/lo frags
    float* base1 = (float*)alloc(128 * 4);
    float* V1p   = (float*)alloc((size_t)3 * 256 * 128 * 4);
    float* bvv   = (float*)alloc((size_t)3 * 128 * 4);
    float* hf    = (float*)alloc((size_t)NNODES * 128 * 4);
    u16* Ysrc    = (u16*)alloc((size_t)NNODES * 128 * 2);
    u16* Ydst    = (u16*)alloc((size_t)NNODES * 128 * 2);
    float* s_glob= (float*)alloc((size_t)NNODES * 128 * 4);

    (void)hipMemsetAsync(hist, 0, (size_t)NNODES * 4, stream);
    k_hist<<<NEDGES / 256, 256, 0, stream>>>(ei, hist);
    k_scan<<<1, 1024, 0, stream>>>(hist, row_ptr, cursor);
    k_scatter<<<NEDGES / 256, 256, 0, stream>>>(ei, cursor, ssrc, sdst);

    PrepAll pa;
    pa.pmw1 = pmw1; pa.pmb1 = pmb1; pa.Wr = Wr;
    for (int l = 0; l < 3; ++l) {
        pa.bfs[l * 2 + 0] = pmw1 + (size_t)l * 34816;           // Y-src weights (W1 rows 0..127)
        pa.bfs[l * 2 + 1] = pmw1 + (size_t)l * 34816 + 16384;   // Y-dst weights (W1 rows 128..255)
        pa.bfs[6 + l] = phw2 + (size_t)l * 16384;               // V2
        pa.bfs[10 + l] = phw1 + (size_t)l * 32768;              // V1a hi (rows 0..127)
        pa.bfs[13 + l] = phw1 + (size_t)l * 32768;              // V1a lo
        pa.pks[l] = phw1 + (size_t)l * 32768;
        pa.pkd[l] = V1p + (size_t)l * 32768;
    }
    pa.bfs[9] = ow1;
    pa.bfs[16] = nw2;                                           // nw2 hi
    pa.bfs[17] = nw2;                                           // nw2 lo
    pa.BF = BF;
    pa.tptr = tptr; pa.tw1 = tw1; pa.tb1 = tb1; pa.tw2 = tw2; pa.tb2 = tb2;
    pa.nw1 = nw1; pa.nb1 = nb1; pa.base1 = base1;
    k_prep_all<<<535, 256, 0, stream>>>(pa);

    k_prep_m<<<dim3(9, 3), 256, 0, stream>>>(pmw2, pmb2, V1p, Mf, bvv);

    k_h0<<<1250, 256, 0, stream>>>(x, base1, nw1,
            BF + (size_t)16 * 16384, BF + (size_t)17 * 16384, nb2, BF, hf, Ysrc, Ydst);

    (void)hipMemsetAsync(s_glob, 0, (size_t)NNODES * 128 * 4, stream);
    for (int l = 0; l < 3; ++l) {
        k_edge<<<NEDGES / 64, 512, 0, stream>>>(Ysrc, Ydst, x, ssrc, sdst,
                Wr + (size_t)l * 4096, s_glob);
        const u16* YwN = (l < 2) ? (BF + (size_t)(l + 1) * 32768) : nullptr;
        k_node<<<1250, 256, 0, stream>>>(s_glob, row_ptr, hf,
                BF + (size_t)(10 + l) * 16384, BF + (size_t)(13 + l) * 16384,
                Mf + (size_t)(l * 2) * 16384, Mf + (size_t)(l * 2 + 1) * 16384,
                BF + (size_t)(6 + l) * 16384,
                bvv + l * 128, phb1 + l * 128, phb2 + l * 128, lng + l * 128, lnb + l * 128,
                YwN, Ysrc, Ydst,
                BF + (size_t)9 * 16384, ob1, ow2, ob2, out);
    }
}

// Round 9
// 459.104 us; speedup vs baseline: 1.2098x; 1.0176x over previous
//
#include <hip/hip_runtime.h>

typedef unsigned short u16;
typedef unsigned int u32;

#define NNODES 20000
#define NEDGES 640000
// GAMMA = 1/(2*(sqrt(2)/15)^2) = 56.25 exactly
#define RBF_GAMMA 56.25f
#define SQRT2 1.4142135623730951f
#define PITCH 132    // fp32 LDS row pitch
#define BPITCH 136   // bf16 LDS row pitch (u16)

typedef __bf16 bf16x8 __attribute__((ext_vector_type(8)));
typedef __bf16 bf16x2 __attribute__((ext_vector_type(2)));
typedef float f32x4 __attribute__((ext_vector_type(4)));

__device__ __forceinline__ float b2f(u16 u) {
    union { float f; u32 i; } x; x.i = ((u32)u) << 16; return x.f;
}
__device__ __forceinline__ float hi2f(u32 w) {
    union { float f; u32 i; } x; x.i = w & 0xffff0000u; return x.f;
}
__device__ __forceinline__ float lo2f(u32 w) {
    union { float f; u32 i; } x; x.i = w << 16; return x.f;
}
__device__ __forceinline__ u16 f2b(float f) {
    union { float f; u32 i; } x; x.f = f;
    u32 r = (x.i + 0x7fffu + ((x.i >> 16) & 1u)) >> 16;
    return (u16)r;
}
// pack 2 fp32 -> 2 bf16 (RNE)
__device__ __forceinline__ u32 pack2(float a, float b) {
#if __has_builtin(__builtin_amdgcn_cvt_pk_bf16_f32)
    union { bf16x2 v; u32 u; } x;
    x.v = __builtin_amdgcn_cvt_pk_bf16_f32(a, b);
    return x.u;
#else
    return (u32)f2b(a) | ((u32)f2b(b) << 16);
#endif
}
__device__ __forceinline__ float silu(float v) {
    return v * __builtin_amdgcn_rcpf(1.0f + __expf(-v));
}

// ---------------- sort by dst (counting sort) ----------------
__global__ __launch_bounds__(256) void k_hist(const int* __restrict__ ei, int* __restrict__ hist) {
    int e = blockIdx.x * 256 + threadIdx.x;
    atomicAdd(&hist[ei[NEDGES + e]], 1);
}

__global__ __launch_bounds__(1024) void k_scan(const int* __restrict__ hist,
                                               int* __restrict__ row_ptr,
                                               int* __restrict__ cursor) {
    __shared__ int psum[1024];
    int t = threadIdx.x;
    int base = t * 20;
    int s = 0;
    if (base < NNODES)
        for (int i = 0; i < 20; ++i) s += hist[base + i];
    psum[t] = s;
    __syncthreads();
    for (int off = 1; off < 1024; off <<= 1) {
        int v = (t >= off) ? psum[t - off] : 0;
        __syncthreads();
        psum[t] += v;
        __syncthreads();
    }
    int excl = psum[t] - s;
    if (base < NNODES) {
        int run = excl;
        for (int i = 0; i < 20; ++i) {
            row_ptr[base + i] = run;
            cursor[base + i] = run;
            run += hist[base + i];
        }
    }
    if (t == 1023) row_ptr[NNODES] = psum[1023];
}

// ---------------- merged prep: Wr + 18 bf16 B-frags + time MLP + M-prep + scatter ----------------
// blocks [0,150): ids [0,38400): [0,1536) Wr frags; [1536,38400) BF frags
// block 150: time embedding -> te -> base1
// blocks [151,178): M = W2 @ V1b -> hi/lo frags, bv = b2 @ V1b   (reads phw1 directly)
// blocks [178,2678): counting-sort scatter
struct PrepAll {
    const float* pmw1; const float* pmb1; u16* Wr;
    const float* bfs[18]; u16* BF;
    const int* tptr;
    const float* tw1; const float* tb1; const float* tw2; const float* tb2;
    const float* nw1; const float* nb1; float* base1;
    const float* pmw2; const float* pmb2; const float* phw1;
    u16* Mf; float* bvv;
    const int* ei; int* cursor; int* ssrc; int* sdst;
};
__global__ __launch_bounds__(256) void k_prep_all(PrepAll pa) {
    const int tid = threadIdx.x;
    const int bx = blockIdx.x;
    __shared__ float smem[16 * PITCH + 128];   // union: W2L[16][PITCH]+b2L | emb/hid/te
    if (bx >= 178) {
        // ---- scatter ----
        int e = (bx - 178) * 256 + tid;
        int d = pa.ei[NEDGES + e];
        int pos = atomicAdd(&pa.cursor[d], 1);
        pa.ssrc[pos] = pa.ei[e];
        pa.sdst[pos] = d;
        return;
    }
    if (bx >= 151) {
        // ---- M-prep: M = W2 @ V1b (direct phw1 reads), bv = b2 @ V1b ----
        int pid = bx - 151;
        int l = pid / 9, sub = pid - l * 9;
        const float* V1bL = pa.phw1 + (size_t)l * 32768 + 16384;   // rows 128..255
        const int w = tid >> 6, lane = tid & 63;
        const int cg = lane & 15, ng = lane >> 4;
        const int jc0 = w * 32 + cg * 2, jc1 = jc0 + 1;
        float (*W2L)[PITCH] = (float (*)[PITCH])smem;
        float* b2L = smem + 16 * PITCH;
        if (sub < 8) {
            const float4* src = (const float4*)(pa.pmw2 + (size_t)l * 16384 + sub * 16 * 128);
            for (int q = tid; q < 512; q += 256) {
                int row = q >> 5, part = q & 31;
                *(float4*)&W2L[row][part * 4] = src[q];
            }
            __syncthreads();
            int r0 = ng * 4;
            float acc[4][2];
            #pragma unroll
            for (int n = 0; n < 4; ++n) { acc[n][0] = 0.f; acc[n][1] = 0.f; }
            for (int mm = 0; mm < 32; ++mm) {
                const float* rp_ = V1bL + (size_t)(mm * 4) * 128 + jc0;
                float2 w0 = *(const float2*)(rp_);
                float2 w1 = *(const float2*)(rp_ + 128);
                float2 w2 = *(const float2*)(rp_ + 256);
                float2 w3 = *(const float2*)(rp_ + 384);
                #pragma unroll
                for (int n = 0; n < 4; ++n) {
                    const float* s4 = &W2L[r0 + n][mm * 4];
                    acc[n][0] = fmaf(w0.x, s4[0], fmaf(w1.x, s4[1],
                                 fmaf(w2.x, s4[2], fmaf(w3.x, s4[3], acc[n][0]))));
                    acc[n][1] = fmaf(w0.y, s4[0], fmaf(w1.y, s4[1],
                                 fmaf(w2.y, s4[2], fmaf(w3.y, s4[3], acc[n][1]))));
                }
            }
            u16* Mfh = pa.Mf + (size_t)(l * 2) * 16384;
            u16* Mfl = Mfh + 16384;
            #pragma unroll
            for (int n = 0; n < 4; ++n) {
                int kg = sub * 16 + r0 + n;
                int kc = kg >> 5, klane = (kg >> 3) & 3, j = kg & 7;
                #pragma unroll
                for (int c = 0; c < 2; ++c) {
                    int col = c ? jc1 : jc0;
                    float v = acc[n][c];
                    u16 h = f2b(v);
                    // element offset = (kc*8 + nt)*512 + lane*8 + j, lane = 16*klane + (col&15)
                    size_t idx = (size_t)((kc * 8 + (col >> 4)) * 512
                                          + ((col & 15) + 16 * klane) * 8 + j);
                    Mfh[idx] = h;
                    Mfl[idx] = f2b(v - b2f(h));
                }
            }
        } else {
            if (tid < 128) b2L[tid] = pa.pmb2[l * 128 + tid];
            __syncthreads();
            if (ng == 0) {
                float a0 = 0.f, a1 = 0.f;
                for (int mm = 0; mm < 32; ++mm) {
                    const float* rp_ = V1bL + (size_t)(mm * 4) * 128 + jc0;
                    float2 w0 = *(const float2*)(rp_);
                    float2 w1 = *(const float2*)(rp_ + 128);
                    float2 w2 = *(const float2*)(rp_ + 256);
                    float2 w3 = *(const float2*)(rp_ + 384);
                    const float* s4 = &b2L[mm * 4];
                    a0 = fmaf(w0.x, s4[0], fmaf(w1.x, s4[1],
                          fmaf(w2.x, s4[2], fmaf(w3.x, s4[3], a0))));
                    a1 = fmaf(w0.y, s4[0], fmaf(w1.y, s4[1],
                          fmaf(w2.y, s4[2], fmaf(w3.y, s4[3], a1))));
                }
                pa.bvv[l * 128 + jc0] = a0;
                pa.bvv[l * 128 + jc1] = a1;
            }
        }
        return;
    }
    if (bx == 150) {
        // ---- time embedding -> te -> base1 ----
        float* emb = smem;
        float* hid = smem + 128;
        float* te = smem + 256;
        int j = tid;
        if (j < 128) {
            int raw = pa.tptr[0];
            float tv;
            if (raw >= 0 && raw < (1 << 24)) tv = (float)raw;
            else tv = __int_as_float(raw);
            float fr = expf(-9.210340371976184f * (float)(j & 63) / 63.0f);
            float a = tv * fr;
            emb[j] = (j < 64) ? sinf(a) : cosf(a);
        }
        __syncthreads();
        if (j < 128) {
            float acc = pa.tb1[j];
            for (int k = 0; k < 128; ++k) acc += emb[k] * pa.tw1[k * 128 + j];
            hid[j] = silu(acc);
        }
        __syncthreads();
        if (j < 128) {
            float acc = pa.tb2[j];
            for (int k = 0; k < 128; ++k) acc += hid[k] * pa.tw2[k * 128 + j];
            te[j] = acc;
        }
        __syncthreads();
        if (j < 128) {
            float acc = pa.nb1[j];
            for (int k = 0; k < 128; ++k) acc += te[k] * pa.nw1[(3 + k) * 128 + j];
            pa.base1[j] = acc;
        }
        return;
    }
    int id = bx * 256 + tid;
    if (id < 1536) {
        // ---- rbf-part W1 rows 256..271 + b1 -> Wr frags ----
        int l = id / 512; int r = id - l * 512;
        int nt = r >> 6, lane = r & 63;
        int col = nt * 16 + (lane & 15);
        alignas(16) u16 tmp[8];
        #pragma unroll
        for (int jj = 0; jj < 8; ++jj) {
            int kk = (lane >> 4) * 8 + jj;
            float v = 0.f;
            if (kk < 16) v = pa.pmw1[l * 34816 + (256 + kk) * 128 + col];
            else if (kk == 16) v = pa.pmb1[l * 128 + col];
            tmp[jj] = f2b(v);
        }
        *(uint4*)(pa.Wr + (size_t)id * 8) = *(const uint4*)tmp;
    } else {
        // ---- 18 fp32[128][128] -> bf16 B-frags (hi: 0..12,16; lo: 13..15,17) ----
        int id2 = id - 1536;
        int mat = id2 >> 11;
        bool lomode = (mat >= 13 && mat != 16);
        int r = id2 & 2047;
        int kc = r >> 9;
        int r2 = r & 511;
        int nt = r2 >> 6, lane = r2 & 63;
        int col = nt * 16 + (lane & 15);
        int kb = kc * 32 + (lane >> 4) * 8;
        const float* src = pa.bfs[mat];
        alignas(16) u16 tmp[8];
        #pragma unroll
        for (int jj = 0; jj < 8; ++jj) {
            float v = src[(kb + jj) * 128 + col];
            u16 h = f2b(v);
            tmp[jj] = lomode ? f2b(v - b2f(h)) : h;
        }
        *(uint4*)(pa.BF + (size_t)id2 * 8) = *(const uint4*)tmp;
    }
}

// ---------------- input node MLP (MFMA hi/lo GEMM2) + MFMA Ysrc/Ydst + s_glob zero ----------------
__global__ __launch_bounds__(256) void k_h0(const float* __restrict__ x, const float* __restrict__ base1,
        const float* __restrict__ nw1, const u16* __restrict__ nw2h, const u16* __restrict__ nw2l,
        const float* __restrict__ nb2, const u16* __restrict__ Yw,
        float* __restrict__ hf, u16* __restrict__ Ysrc, u16* __restrict__ Ydst,
        float* __restrict__ s_glob) {
    const int tid = threadIdx.x;
    const int w = tid >> 6, lane = tid & 63;
    const int cg = lane & 15, ng = lane >> 4;
    const int jc0 = w * 32 + cg * 2, jc1 = jc0 + 1;
    const int n0 = ng * 4;
    const int base = blockIdx.x * 16;
    const int lrow = lane & 15, quad = lane >> 4;
    __shared__ alignas(16) float xl[16][4];
    __shared__ alignas(16) u16 hih[16 * BPITCH], hil[16 * BPITCH];
    __shared__ alignas(16) u16 hb16[16 * BPITCH];
    {   // zero this block's s_glob slice (replaces the global memset dispatch)
        float4* sg = (float4*)(s_glob + (size_t)base * 128);
        for (int q = tid; q < 512; q += 256) sg[q] = make_float4(0.f, 0.f, 0.f, 0.f);
    }
    if (tid < 48) { int n = tid / 3, cc = tid - n * 3; xl[n][cc] = x[(size_t)(base + n) * 3 + cc]; }
    __syncthreads();
    {
        float w0a = nw1[jc0], w0b = nw1[jc1];
        float w1a = nw1[128 + jc0], w1b = nw1[128 + jc1];
        float w2a = nw1[256 + jc0], w2b = nw1[256 + jc1];
        float ba = base1[jc0], bb = base1[jc1];
        #pragma unroll
        for (int n = 0; n < 4; ++n) {
            int row = n0 + n;
            float x0 = xl[row][0], x1 = xl[row][1], x2 = xl[row][2];
            float va = silu(ba + x0 * w0a + x1 * w1a + x2 * w2a);
            float vb = silu(bb + x0 * w0b + x1 * w1b + x2 * w2b);
            u32 hw = pack2(va, vb);
            *(u32*)&hih[row * BPITCH + jc0] = hw;
            *(u32*)&hil[row * BPITCH + jc0] = pack2(va - lo2f(hw), vb - hi2f(hw));
        }
    }
    __syncthreads();
    // GEMM2 (MFMA hi/lo): h = hid @ nw2 + nb2 -> hf (fp32) + hb16 (bf16)
    {
        bf16x8 ah[4], al[4];
        #pragma unroll
        for (int kc = 0; kc < 4; ++kc) {
            ah[kc] = *(const bf16x8*)(hih + lrow * BPITCH + kc * 32 + quad * 8);
            al[kc] = *(const bf16x8*)(hil + lrow * BPITCH + kc * 32 + quad * 8);
        }
        #pragma unroll
        for (int t = 0; t < 2; ++t) {
            int nt = w * 2 + t;
            f32x4 a4 = {0.f, 0.f, 0.f, 0.f};
            #pragma unroll
            for (int kc = 0; kc < 4; ++kc) {
                size_t o = (size_t)((kc * 8 + nt) * 512 + lane * 8);
                bf16x8 bh = *(const bf16x8*)(nw2h + o);
                bf16x8 bl = *(const bf16x8*)(nw2l + o);
                a4 = __builtin_amdgcn_mfma_f32_16x16x32_bf16(ah[kc], bh, a4, 0, 0, 0);
                a4 = __builtin_amdgcn_mfma_f32_16x16x32_bf16(al[kc], bh, a4, 0, 0, 0);
                a4 = __builtin_amdgcn_mfma_f32_16x16x32_bf16(ah[kc], bl, a4, 0, 0, 0);
            }
            int colC = nt * 16 + lrow;
            float bC = nb2[colC];
            #pragma unroll
            for (int r = 0; r < 4; ++r) {
                int R = quad * 4 + r;
                float v = a4[r] + bC;
                hf[(size_t)(base + R) * 128 + colC] = v;
                hb16[R * BPITCH + colC] = f2b(v);
            }
        }
    }
    __syncthreads();
    // MFMA Y-GEMMs: wave w -> mat = w>>1, nt-half = w&1
    {
        const int mat = w >> 1, half = w & 1;
        bf16x8 a[4];
        #pragma unroll
        for (int kc = 0; kc < 4; ++kc)
            a[kc] = *(const bf16x8*)(hb16 + lrow * BPITCH + kc * 32 + quad * 8);
        u16* dst = mat ? Ydst : Ysrc;
        #pragma unroll
        for (int t = 0; t < 4; ++t) {
            int nt = half * 4 + t;
            f32x4 a4 = {0.f, 0.f, 0.f, 0.f};
            #pragma unroll
            for (int kc = 0; kc < 4; ++kc) {
                bf16x8 b = *(const bf16x8*)(Yw + (size_t)(((mat * 4 + kc) * 8 + nt) * 512 + lane * 8));
                a4 = __builtin_amdgcn_mfma_f32_16x16x32_bf16(a[kc], b, a4, 0, 0, 0);
            }
            #pragma unroll
            for (int r = 0; r < 4; ++r)
                dst[(size_t)(base + quad * 4 + r) * 128 + nt * 16 + lrow] = f2b(a4[r]);
        }
    }
}

// ---------------- edge kernel (proven): 512 threads, bf16 sst, 2x8-row epilogue ----------------
__global__ __launch_bounds__(512, 8) void k_edge(
        const u16* __restrict__ Ysrc, const u16* __restrict__ Ydst,
        const float* __restrict__ x,
        const int* __restrict__ ssrc, const int* __restrict__ sdst,
        const u16* __restrict__ Wr,
        float* __restrict__ s_glob) {
    __shared__ alignas(16) u16 sst[128 * 72];   // [col][row] bf16, pitch 72
    __shared__ alignas(16) u16 ys[64 * 128];    // staged Ysrc rows
    __shared__ float rv[64];
    __shared__ alignas(16) int s_d[65];
    __shared__ int s_s[64];
    const int tid = threadIdx.x;
    const int e0 = blockIdx.x * 64;
    if (tid < 64) {
        int s = ssrc[e0 + tid], d = sdst[e0 + tid];
        s_s[tid] = s; s_d[tid] = d;
        float ddx = x[s * 3] - x[d * 3];
        float ddy = x[s * 3 + 1] - x[d * 3 + 1];
        rv[tid] = sqrtf(ddx * ddx + ddy * ddy + 1e-8f);
    } else if (tid == 64) {
        s_d[64] = -1;
    }
    __syncthreads();
    #pragma unroll
    for (int i = 0; i < 2; ++i) {
        int cch = tid + i * 512;
        int e = cch >> 4, part = cch & 15;
        *(uint4*)(ys + e * 128 + part * 8) = *(const uint4*)(Ysrc + (size_t)s_s[e] * 128 + part * 8);
    }
    const int w = tid >> 6, lane = tid & 63;
    const int m = w & 3, nh = w >> 2;
    const int lrow = lane & 15, quad = lane >> 4;
    float r = rv[m * 16 + lrow];
    union { bf16x8 v; u16 u[8]; } af;
    #pragma unroll
    for (int j = 0; j < 8; ++j) {
        int kk = quad * 8 + j;
        float v;
        if (kk < 16) {
            float dd = r - SQRT2 * (float)kk / 15.0f;
            v = __expf(-RBF_GAMMA * dd * dd);
        } else v = (kk == 16) ? 1.0f : 0.0f;
        af.u[j] = f2b(v);
    }
    {
        const u16* Bp = Wr + lane * 8;
        #pragma unroll
        for (int t = 0; t < 4; ++t) {
            int nt = nh * 4 + t;
            f32x4 a4 = {0.f, 0.f, 0.f, 0.f};
            bf16x8 b = *(const bf16x8*)(Bp + nt * 512);
            a4 = __builtin_amdgcn_mfma_f32_16x16x32_bf16(af.v, b, a4, 0, 0, 0);
            int col = nt * 16 + lrow;
            u32 lo = pack2(a4[0], a4[1]);
            u32 hi = pack2(a4[2], a4[3]);
            *(uint2*)(sst + col * 72 + m * 16 + quad * 4) = make_uint2(lo, hi);
        }
    }
    __syncthreads();
    {
        const int col = tid & 127, q = tid >> 7;
        const int r0 = q * 16;
        int nds[17];
        #pragma unroll
        for (int b = 0; b < 4; ++b)
            *(int4*)&nds[b * 4] = *(const int4*)&s_d[r0 + b * 4];
        nds[16] = s_d[r0 + 16];
        float a = 0.f;
        int cd = nds[0];
        float yd = b2f(Ydst[(size_t)cd * 128 + col]);
        #pragma unroll
        for (int h = 0; h < 2; ++h) {
            uint4 c0 = *(const uint4*)(sst + col * 72 + r0 + h * 8);
            float sv8[8];
            sv8[0] = lo2f(c0.x); sv8[1] = hi2f(c0.x);
            sv8[2] = lo2f(c0.y); sv8[3] = hi2f(c0.y);
            sv8[4] = lo2f(c0.z); sv8[5] = hi2f(c0.z);
            sv8[6] = lo2f(c0.w); sv8[7] = hi2f(c0.w);
            #pragma unroll
            for (int i = 0; i < 8; ++i) {
                int rr = r0 + h * 8 + i;
                int nd = nds[h * 8 + i + 1];
                float v = sv8[i] + b2f(ys[rr * 128 + col]) + yd;
                float e = __expf(-v);
                a = fmaf(v, __builtin_amdgcn_rcpf(1.0f + e), a);
                bool last = (h == 1 && i == 7);
                if (last || nd != cd) {
                    atomicAdd(&s_glob[(size_t)cd * 128 + col], a);
                    a = 0.f;
                    if (!last && nd != cd)
                        yd = b2f(Ydst[(size_t)nd * 128 + col]);
                }
                cd = nd;
            }
        }
    }
}

// ---------------- node update: GEMM2' via MFMA (hi/lo bf16), GEMM3 via MFMA,
//                  MFMA Ysrc/Ydst (l<2) or fused output MLP (l==2)
//                  LDS-aliased: ybf over hvh, xs over svh/svl (25.5 KB -> 6 blocks/CU) ----------------
__global__ __launch_bounds__(256) void k_node(float* __restrict__ s_glob, const int* __restrict__ row_ptr,
        float* __restrict__ hf,
        const u16* __restrict__ V1h, const u16* __restrict__ V1l,
        const u16* __restrict__ Mh, const u16* __restrict__ Ml,
        const u16* __restrict__ V2bf,
        const float* __restrict__ bv, const float* __restrict__ c1, const float* __restrict__ c2,
        const float* __restrict__ lng, const float* __restrict__ lnb,
        const u16* __restrict__ Yw,
        u16* __restrict__ Ysrc, u16* __restrict__ Ydst,
        const u16* __restrict__ ow1bf, const float* __restrict__ ob1,
        const float* __restrict__ ow2, const float* __restrict__ ob2,
        float* __restrict__ out) {
    const int tid = threadIdx.x;
    const int w = tid >> 6, lane = tid & 63;
    const int cg = lane & 15, ng = lane >> 4;
    const int jc0 = w * 32 + cg * 2, jc1 = jc0 + 1;
    const int n0 = ng * 4;
    const int base = blockIdx.x * 16;
    const int lrow = lane & 15, quad = lane >> 4;
    __shared__ alignas(16) float hv[16][PITCH];          // 8448 B
    __shared__ alignas(16) u16 T[4 * 16 * BPITCH];       // 17408 B, aliased below
    __shared__ float mv[16][2];
    __shared__ int rp[17];
    u16* hvh = T;
    u16* hvl = T + 16 * BPITCH;
    u16* svh = T + 2 * 16 * BPITCH;
    u16* svl = T + 3 * 16 * BPITCH;
    u16* ybf = T;                                        // aliases hvh (dead after reg loads)
    float (*xs)[PITCH] = (float (*)[PITCH])svh;          // aliases svh+svl (8448 <= 8704)

    if (tid < 17) rp[tid] = row_ptr[base + tid];
    {
        const float4* sg4 = (const float4*)(s_glob + (size_t)base * 128);
        float4* sg4w = (float4*)(s_glob + (size_t)base * 128);
        const float4* hg4 = (const float4*)(hf + (size_t)base * 128);
        for (int q = tid; q < 512; q += 256) {
            int row = q >> 5, part = q & 31;
            float4 s = sg4[q];
            float4 h = hg4[q];
            if (Yw != nullptr) sg4w[q] = make_float4(0.f, 0.f, 0.f, 0.f);
            *(float4*)&hv[row][part * 4] = h;
            u32 hw0 = pack2(h.x, h.y), hw1 = pack2(h.z, h.w);
            *(uint2*)&hvh[row * BPITCH + part * 4] = make_uint2(hw0, hw1);
            u32 hl0 = pack2(h.x - lo2f(hw0), h.y - hi2f(hw0));
            u32 hl1 = pack2(h.z - lo2f(hw1), h.w - hi2f(hw1));
            *(uint2*)&hvl[row * BPITCH + part * 4] = make_uint2(hl0, hl1);
            u32 sw0 = pack2(s.x, s.y), sw1 = pack2(s.z, s.w);
            *(uint2*)&svh[row * BPITCH + part * 4] = make_uint2(sw0, sw1);
            u32 sl0 = pack2(s.x - lo2f(sw0), s.y - hi2f(sw0));
            u32 sl1 = pack2(s.z - lo2f(sw1), s.w - hi2f(sw1));
            *(uint2*)&svl[row * BPITCH + part * 4] = make_uint2(sl0, sl1);
        }
    }
    __syncthreads();

    // ---- GEMM2' (MFMA, hi/lo bf16): u_pre = hv@V1a + sv@M + deg*bv + c1 ; uv = silu -> ybf ----
    {
        bf16x8 ahh[4], ahl[4], ash[4], asl[4];
        #pragma unroll
        for (int kc = 0; kc < 4; ++kc) {
            ahh[kc] = *(const bf16x8*)(hvh + lrow * BPITCH + kc * 32 + quad * 8);
            ahl[kc] = *(const bf16x8*)(hvl + lrow * BPITCH + kc * 32 + quad * 8);
            ash[kc] = *(const bf16x8*)(svh + lrow * BPITCH + kc * 32 + quad * 8);
            asl[kc] = *(const bf16x8*)(svl + lrow * BPITCH + kc * 32 + quad * 8);
        }
        float dg[4];
        #pragma unroll
        for (int r = 0; r < 4; ++r)
            dg[r] = (float)(rp[quad * 4 + r + 1] - rp[quad * 4 + r]);
        __syncthreads();   // all reg loads done before ybf (aliases hvh) is written
        #pragma unroll
        for (int t = 0; t < 2; ++t) {
            int nt = w * 2 + t;
            f32x4 a4 = {0.f, 0.f, 0.f, 0.f};
            #pragma unroll
            for (int kc = 0; kc < 4; ++kc) {
                size_t o = (size_t)((kc * 8 + nt) * 512 + lane * 8);
                bf16x8 bh = *(const bf16x8*)(V1h + o);
                bf16x8 bl = *(const bf16x8*)(V1l + o);
                a4 = __builtin_amdgcn_mfma_f32_16x16x32_bf16(ahh[kc], bh, a4, 0, 0, 0);
                a4 = __builtin_amdgcn_mfma_f32_16x16x32_bf16(ahl[kc], bh, a4, 0, 0, 0);
                a4 = __builtin_amdgcn_mfma_f32_16x16x32_bf16(ahh[kc], bl, a4, 0, 0, 0);
                bf16x8 mh = *(const bf16x8*)(Mh + o);
                bf16x8 ml = *(const bf16x8*)(Ml + o);
                a4 = __builtin_amdgcn_mfma_f32_16x16x32_bf16(ash[kc], mh, a4, 0, 0, 0);
                a4 = __builtin_amdgcn_mfma_f32_16x16x32_bf16(asl[kc], mh, a4, 0, 0, 0);
                a4 = __builtin_amdgcn_mfma_f32_16x16x32_bf16(ash[kc], ml, a4, 0, 0, 0);
            }
            int colC = nt * 16 + lrow;
            float bvC = bv[colC], c1C = c1[colC];
            #pragma unroll
            for (int r = 0; r < 4; ++r) {
                float u = a4[r] + dg[r] * bvC + c1C;
                ybf[(quad * 4 + r) * BPITCH + colC] = f2b(silu(u));
            }
        }
    }
    __syncthreads();   // uv(bf16) ready; svh/svl dead -> xs region free
    // ---- GEMM3 (MFMA): o = uv @ V2 + c2 ; xj = hv + o -> xs (C-layout) ----
    {
        bf16x8 a[4];
        #pragma unroll
        for (int kc = 0; kc < 4; ++kc)
            a[kc] = *(const bf16x8*)(ybf + lrow * BPITCH + kc * 32 + quad * 8);
        #pragma unroll
        for (int t = 0; t < 2; ++t) {
            int nt = w * 2 + t;
            f32x4 a4 = {0.f, 0.f, 0.f, 0.f};
            #pragma unroll
            for (int kc = 0; kc < 4; ++kc) {
                bf16x8 b = *(const bf16x8*)(V2bf + (size_t)((kc * 8 + nt) * 512 + lane * 8));
                a4 = __builtin_amdgcn_mfma_f32_16x16x32_bf16(a[kc], b, a4, 0, 0, 0);
            }
            int colC = nt * 16 + lrow;
            float c2v = c2[colC];
            #pragma unroll
            for (int r = 0; r < 4; ++r) {
                int R = quad * 4 + r;
                xs[R][colC] = a4[r] + c2v + hv[R][colC];
            }
        }
    }
    __syncthreads();
    // ---- LN reduce ----
    {
        int row = tid >> 4, part = tid & 15;
        float4 a = *(const float4*)&xs[row][part * 8];
        float4 b = *(const float4*)&xs[row][part * 8 + 4];
        float s1 = a.x + a.y + a.z + a.w + b.x + b.y + b.z + b.w;
        float s2 = a.x * a.x + a.y * a.y + a.z * a.z + a.w * a.w
                 + b.x * b.x + b.y * b.y + b.z * b.z + b.w * b.w;
        #pragma unroll
        for (int mq = 1; mq < 16; mq <<= 1) {
            s1 += __shfl_xor(s1, mq, 64);
            s2 += __shfl_xor(s2, mq, 64);
        }
        if (part == 0) { mv[row][0] = s1; mv[row][1] = s2; }
    }
    __syncthreads();
    // ---- LN apply (writes y to bf16 tile; hf only when another layer follows) ----
    {
        float ga = lng[jc0], gb = lng[jc1];
        float bba = lnb[jc0], bbb = lnb[jc1];
        #pragma unroll
        for (int n = 0; n < 4; ++n) {
            int row = n0 + n;
            float mu = mv[row][0] * (1.0f / 128.0f);
            float var = mv[row][1] * (1.0f / 128.0f) - mu * mu;
            float rs = rsqrtf(var + 1e-5f);
            float y0 = (xs[row][jc0] - mu) * rs * ga + bba;
            float y1 = (xs[row][jc1] - mu) * rs * gb + bbb;
            if (Yw != nullptr)
                *(float2*)&hf[(size_t)(base + row) * 128 + jc0] = make_float2(y0, y1);
            *(u32*)&ybf[row * BPITCH + jc0] = pack2(y0, y1);
        }
    }
    if (Yw != nullptr) {
        __syncthreads();
        const int mat = w >> 1, half = w & 1;
        bf16x8 a[4];
        #pragma unroll
        for (int kc = 0; kc < 4; ++kc)
            a[kc] = *(const bf16x8*)(ybf + lrow * BPITCH + kc * 32 + quad * 8);
        u16* dst = mat ? Ydst : Ysrc;
        #pragma unroll
        for (int t = 0; t < 4; ++t) {
            int nt = half * 4 + t;
            f32x4 a4 = {0.f, 0.f, 0.f, 0.f};
            #pragma unroll
            for (int kc = 0; kc < 4; ++kc) {
                bf16x8 b = *(const bf16x8*)(Yw + (size_t)(((mat * 4 + kc) * 8 + nt) * 512 + lane * 8));
                a4 = __builtin_amdgcn_mfma_f32_16x16x32_bf16(a[kc], b, a4, 0, 0, 0);
            }
            #pragma unroll
            for (int r = 0; r < 4; ++r)
                dst[(size_t)(base + quad * 4 + r) * 128 + nt * 16 + lrow] = f2b(a4[r]);
        }
    } else {
        // ---- fused output MLP: hid2 = silu(y @ ow1 + ob1) -> hv ; out = hid2 @ ow2 + ob2 ----
        __syncthreads();
        {
            bf16x8 a[4];
            #pragma unroll
            for (int kc = 0; kc < 4; ++kc)
                a[kc] = *(const bf16x8*)(ybf + lrow * BPITCH + kc * 32 + quad * 8);
            #pragma unroll
            for (int t = 0; t < 2; ++t) {
                int nt = w * 2 + t;
                f32x4 a4 = {0.f, 0.f, 0.f, 0.f};
                #pragma unroll
                for (int kc = 0; kc < 4; ++kc) {
                    bf16x8 b = *(const bf16x8*)(ow1bf + (size_t)((kc * 8 + nt) * 512 + lane * 8));
                    a4 = __builtin_amdgcn_mfma_f32_16x16x32_bf16(a[kc], b, a4, 0, 0, 0);
                }
                int colC = nt * 16 + lrow;
                float b1v = ob1[colC];
                #pragma unroll
                for (int r = 0; r < 4; ++r)
                    hv[quad * 4 + r][colC] = silu(a4[r] + b1v);
            }
        }
        __syncthreads();
        {
            int row = tid >> 4, s = tid & 15;
            float p0 = 0.f, p1 = 0.f, p2 = 0.f;
            #pragma unroll
            for (int kk2 = 0; kk2 < 8; ++kk2) {
                int k = s * 8 + kk2;
                float h2 = hv[row][k];
                p0 = fmaf(h2, ow2[k * 3 + 0], p0);
                p1 = fmaf(h2, ow2[k * 3 + 1], p1);
                p2 = fmaf(h2, ow2[k * 3 + 2], p2);
            }
            #pragma unroll
            for (int mq = 1; mq < 16; mq <<= 1) {
                p0 += __shfl_xor(p0, mq, 64);
                p1 += __shfl_xor(p1, mq, 64);
                p2 += __shfl_xor(p2, mq, 64);
            }
            if (s == 0) {
                float* o = out + (size_t)(base + row) * 3;
                o[0] = p0 + ob2[0];
                o[1] = p1 + ob2[1];
                o[2] = p2 + ob2[2];
            }
        }
    }
}

extern "C" void kernel_launch(void* const* d_in, const int* in_sizes, int n_in,
                              void* d_out, int out_size, void* d_ws, size_t ws_size,
                              hipStream_t stream) {
    const float* x    = (const float*)d_in[0];
    const int* ei     = (const int*)d_in[1];
    const int* tptr   = (const int*)d_in[2];
    const float* tw1  = (const float*)d_in[3];
    const float* tb1  = (const float*)d_in[4];
    const float* tw2  = (const float*)d_in[5];
    const float* tb2  = (const float*)d_in[6];
    const float* nw1  = (const float*)d_in[7];
    const float* nb1  = (const float*)d_in[8];
    const float* nw2  = (const float*)d_in[9];
    const float* nb2  = (const float*)d_in[10];
    const float* pmw1 = (const float*)d_in[11];
    const float* pmb1 = (const float*)d_in[12];
    const float* pmw2 = (const float*)d_in[13];
    const float* pmb2 = (const float*)d_in[14];
    const float* phw1 = (const float*)d_in[15];
    const float* phb1 = (const float*)d_in[16];
    const float* phw2 = (const float*)d_in[17];
    const float* phb2 = (const float*)d_in[18];
    const float* lng  = (const float*)d_in[19];
    const float* lnb  = (const float*)d_in[20];
    const float* ow1  = (const float*)d_in[21];
    const float* ob1  = (const float*)d_in[22];
    const float* ow2  = (const float*)d_in[23];
    const float* ob2  = (const float*)d_in[24];
    float* out = (float*)d_out;

    char* wsp = (char*)d_ws;
    size_t off = 0;
    auto alloc = [&](size_t bytes) -> void* {
        void* p = wsp + off;
        off += (bytes + 255) & ~(size_t)255;
        return p;
    };
    int* hist    = (int*)alloc((size_t)NNODES * 4);
    int* cursor  = (int*)alloc((size_t)NNODES * 4);
    int* row_ptr = (int*)alloc((size_t)(NNODES + 1) * 4);
    int* ssrc    = (int*)alloc((size_t)NEDGES * 4);
    int* sdst    = (int*)alloc((size_t)NEDGES * 4);
    u16* Wr      = (u16*)alloc((size_t)3 * 8 * 64 * 8 * 2);
    u16* BF      = (u16*)alloc((size_t)18 * 16384 * 2);   // 6 Yw + 3 V2 + ow1 + 3 V1h + 3 V1l + nw2h + nw2l
    u16* Mf      = (u16*)alloc((size_t)6 * 16384 * 2);    // per layer M hi/lo frags
    float* base1 = (float*)alloc(128 * 4);
    float* bvv   = (float*)alloc((size_t)3 * 128 * 4);
    float* hf    = (float*)alloc((size_t)NNODES * 128 * 4);
    u16* Ysrc    = (u16*)alloc((size_t)NNODES * 128 * 2);
    u16* Ydst    = (u16*)alloc((size_t)NNODES * 128 * 2);
    float* s_glob= (float*)alloc((size_t)NNODES * 128 * 4);

    (void)hipMemsetAsync(hist, 0, (size_t)NNODES * 4, stream);
    k_hist<<<NEDGES / 256, 256, 0, stream>>>(ei, hist);
    k_scan<<<1, 1024, 0, stream>>>(hist, row_ptr, cursor);

    PrepAll pa;
    pa.pmw1 = pmw1; pa.pmb1 = pmb1; pa.Wr = Wr;
    for (int l = 0; l < 3; ++l) {
        pa.bfs[l * 2 + 0] = pmw1 + (size_t)l * 34816;           // Y-src weights (W1 rows 0..127)
        pa.bfs[l * 2 + 1] = pmw1 + (size_t)l * 34816 + 16384;   // Y-dst weights (W1 rows 128..255)
        pa.bfs[6 + l] = phw2 + (size_t)l * 16384;               // V2
        pa.bfs[10 + l] = phw1 + (size_t)l * 32768;              // V1a hi (rows 0..127)
        pa.bfs[13 + l] = phw1 + (size_t)l * 32768;              // V1a lo
    }
    pa.bfs[9] = ow1;
    pa.bfs[16] = nw2;                                           // nw2 hi
    pa.bfs[17] = nw2;                                           // nw2 lo
    pa.BF = BF;
    pa.tptr = tptr; pa.tw1 = tw1; pa.tb1 = tb1; pa.tw2 = tw2; pa.tb2 = tb2;
    pa.nw1 = nw1; pa.nb1 = nb1; pa.base1 = base1;
    pa.pmw2 = pmw2; pa.pmb2 = pmb2; pa.phw1 = phw1;
    pa.Mf = Mf; pa.bvv = bvv;
    pa.ei = ei; pa.cursor = cursor; pa.ssrc = ssrc; pa.sdst = sdst;
    k_prep_all<<<2678, 256, 0, stream>>>(pa);

    k_h0<<<1250, 256, 0, stream>>>(x, base1, nw1,
            BF + (size_t)16 * 16384, BF + (size_t)17 * 16384, nb2, BF, hf, Ysrc, Ydst, s_glob);

    for (int l = 0; l < 3; ++l) {
        k_edge<<<NEDGES / 64, 512, 0, stream>>>(Ysrc, Ydst, x, ssrc, sdst,
                Wr + (size_t)l * 4096, s_glob);
        const u16* YwN = (l < 2) ? (BF + (size_t)(l + 1) * 32768) : nullptr;
        k_node<<<1250, 256, 0, stream>>>(s_glob, row_ptr, hf,
                BF + (size_t)(10 + l) * 16384, BF + (size_t)(13 + l) * 16384,
                Mf + (size_t)(l * 2) * 16384, Mf + (size_t)(l * 2 + 1) * 16384,
                BF + (size_t)(6 + l) * 16384,
                bvv + l * 128, phb1 + l * 128, phb2 + l * 128, lng + l * 128, lnb + l * 128,
                YwN, Ysrc, Ydst,
                BF + (size_t)9 * 16384, ob1, ow2, ob2, out);
    }
}